// Round 17
// baseline (563.800 us; speedup 1.0000x reference)
//
#include <hip/hip_runtime.h>
#include <hip/hip_bf16.h>

#define NGEN 50000
#define NBUS 80000
#define NRES 10000
#define NTOT 140000
#define EPROD 100000
#define ESERV 100000
#define ETRAN 150000
#define EBACK 50000
#define ETOT  400000
#define HID 128
#define NEGS 0.2f

#define NB_SCAN 547   // ceil(NTOT/256)
#define EB 1563       // ceil(ETOT/256)
#define WB 35000      // NTOT waves of 64 in 256-thread blocks
#define NW16 8750     // NTOT/16 row-groups
#define PGRID 768     // persistent blocks (3/CU) — 1024 regressed twice (R9, R15)
#define AGGW 160      // agg row width (144 real + 16 pad)
#define LINP 172      // padded LDS row for K=160
#define HETP 140      // padded LDS row for K=128

typedef __attribute__((ext_vector_type(8))) short bf16x8;
typedef __attribute__((ext_vector_type(8))) unsigned short u16x8;
typedef __attribute__((ext_vector_type(4))) float f32x4;

__device__ __forceinline__ float lrelu(float x) { return x >= 0.f ? x : NEGS * x; }
__device__ __forceinline__ float b2f(ushort u) { union { float f; uint i; } v; v.i = (uint)u << 16; return v.f; }
__device__ __forceinline__ ushort f2b(float f) {
  union { float f; uint i; } v; v.f = f;
  return (ushort)((v.i + 0x7FFF + ((v.i >> 16) & 1)) >> 16);
}

// ---------------- edge setup (+ degree count) ----------------
__global__ __launch_bounds__(256) void k_setup_edges(
    const int* __restrict__ eip, const int* __restrict__ eis,
    const int* __restrict__ eit, const int* __restrict__ eib,
    const float* __restrict__ eap, const float* __restrict__ eas,
    const float* __restrict__ eat, const float* __restrict__ eab,
    int* __restrict__ esrc, int* __restrict__ edst, float* __restrict__ ea_all,
    int* __restrict__ cnt)
{
  int e = blockIdx.x * 256 + threadIdx.x;
  if (e >= ETOT) return;
  int s, d; float a0, a1;
  if (e < EPROD) { s = eip[e]; d = eip[EPROD + e]; a0 = eap[2*e]; a1 = eap[2*e+1]; }
  else if (e < EPROD+ESERV) { int i = e - EPROD; s = eis[i]; d = eis[ESERV + i]; a0 = eas[2*i]; a1 = eas[2*i+1]; }
  else if (e < EPROD+ESERV+ETRAN) { int i = e - EPROD - ESERV; s = eit[i]; d = eit[ETRAN + i]; a0 = eat[2*i]; a1 = eat[2*i+1]; }
  else { int i = e - EPROD - ESERV - ETRAN; s = eib[i]; d = eib[EBACK + i]; a0 = eab[2*i]; a1 = eab[2*i+1]; }
  esrc[e] = s; edst[e] = d; ea_all[2*e] = a0; ea_all[2*e+1] = a1;
  atomicAdd(&cnt[d], 1);
}

// hierarchical scan
__global__ __launch_bounds__(256) void k_scan1(const int* __restrict__ cnt,
                                               int* __restrict__ rp, int* __restrict__ bsum)
{
  int t = threadIdx.x, i = blockIdx.x * 256 + t;
  int v = (i < NTOT) ? cnt[i] : 0;
  __shared__ int buf[256];
  buf[t] = v; __syncthreads();
  for (int off = 1; off < 256; off <<= 1) {
    int x = (t >= off) ? buf[t - off] : 0;
    __syncthreads(); buf[t] += x; __syncthreads();
  }
  if (i < NTOT) rp[i] = buf[t] - v;
  if (t == 255) bsum[blockIdx.x] = buf[255];
}

__global__ __launch_bounds__(1024) void k_scan2(int* __restrict__ bsum, int nb)
{
  int t = threadIdx.x;
  __shared__ int buf[1024];
  int v = (t < nb) ? bsum[t] : 0;
  buf[t] = v; __syncthreads();
  for (int off = 1; off < 1024; off <<= 1) {
    int x = (t >= off) ? buf[t - off] : 0;
    __syncthreads(); buf[t] += x; __syncthreads();
  }
  if (t < nb) bsum[t] = buf[t] - v;
}

__global__ __launch_bounds__(256) void k_scan3(int* __restrict__ rp, const int* __restrict__ bsum)
{
  int i = blockIdx.x * 256 + threadIdx.x;
  if (i < NTOT) rp[i] += bsum[blockIdx.x];
  if (i == 0) rp[NTOT] = ETOT;
}

// scatter: srcp[pos] = src node; epos[e] = CSR position of edge e
__global__ __launch_bounds__(256) void k_scatter(const int* __restrict__ esrc,
    const int* __restrict__ edst, const int* __restrict__ rp,
    int* __restrict__ fill, int* __restrict__ srcp, int* __restrict__ epos)
{
  int e = blockIdx.x * 256 + threadIdx.x;
  if (e >= ETOT) return;
  int d = edst[e];
  int pos = rp[d] + atomicAdd(&fill[d], 1);
  srcp[pos] = esrc[e];
  epos[e] = pos;
}

// ---------------- weight conversion ----------------
__global__ __launch_bounds__(256) void k_convW(
    const float* __restrict__ pg, const float* __restrict__ pb, const float* __restrict__ pr,
    const float* __restrict__ h1, const float* __restrict__ l1,
    const float* __restrict__ h2, const float* __restrict__ l2,
    const float* __restrict__ h3, const float* __restrict__ l3,
    ushort* __restrict__ dst)
{
  int idx = blockIdx.x * 256 + threadIdx.x;
  if (idx >= 233472) return;
  const float* src; int K, KP, base;
  if (idx < 24576) {
    int s = idx >> 13;
    src = (s == 0) ? pg : (s == 1) ? pb : pr;
    K = (s == 0) ? 39 : 16; KP = 64; base = s * 8192;
  } else {
    int r = idx - 24576, l = r / 69632, q = r % 69632;
    const float* h = (l == 0) ? h1 : (l == 1) ? h2 : h3;
    const float* lw = (l == 0) ? l1 : (l == 1) ? l2 : l3;
    if (q < 49152) { int t = q >> 14; src = h + t * 16384; K = 128; KP = 128; base = 24576 + l * 69632 + t * 16384; }
    else { src = lw; K = 144; KP = 160; base = 24576 + l * 69632 + 49152; }
  }
  int li = idx - base, c = li / KP, k = li % KP;
  dst[idx] = (k < K) ? f2b(src[k * 128 + c]) : (ushort)0;
}

// ---------------- segmented LDS GEMM (input projections only, K<=39) ----------------
struct Seg {
  const void* A; const ushort* Wt; const float* bias;
  int lda, K, M, nb, rbase;
};

__global__ __launch_bounds__(256) void k_mgemm3(Seg s0, Seg s1, Seg s2, int KP, ushort* __restrict__ Cb)
{
  __shared__ ushort As[128][72];
  __shared__ ushort Bs[128][72];
  int bid = blockIdx.x;
  Seg sg = s0;
  if (bid >= s0.nb + s1.nb) { sg = s2; bid -= s0.nb + s1.nb; }
  else if (bid >= s0.nb) { sg = s1; bid -= s0.nb; }

  const int tid = threadIdx.x;
  const int lr = tid & 15, hi = (tid & 63) >> 4;
  const int w = tid >> 6;
  const int wrow = (w >> 1) * 64, wcol = (w & 1) * 64;
  const int brow = bid * 128;

  f32x4 acc[4][4];
#pragma unroll
  for (int m = 0; m < 4; ++m)
#pragma unroll
    for (int n = 0; n < 4; ++n) acc[m][n] = (f32x4){0.f, 0.f, 0.f, 0.f};

  for (int k0 = 0; k0 < KP; k0 += 64) {
#pragma unroll
    for (int p = 0; p < 8; ++p) {
      int li = tid + 256 * p;
      int row = li >> 4, c4 = (li & 15) * 4;
      int gr = brow + row, gk = k0 + c4;
      ushort4 u = make_ushort4(0, 0, 0, 0);
      if (gr < sg.M) {
        const float* A = (const float*)sg.A;
        const float* ar = A + (size_t)gr * sg.lda;
        if (gk + 0 < sg.K) u.x = f2b(ar[gk + 0]);
        if (gk + 1 < sg.K) u.y = f2b(ar[gk + 1]);
        if (gk + 2 < sg.K) u.z = f2b(ar[gk + 2]);
        if (gk + 3 < sg.K) u.w = f2b(ar[gk + 3]);
      }
      *(ushort4*)&As[row][c4] = u;
    }
#pragma unroll
    for (int p = 0; p < 8; ++p) {
      int li = tid + 256 * p;
      int row = li >> 4, c4 = (li & 15) * 4;
      *(ushort4*)&Bs[row][c4] = *(const ushort4*)&sg.Wt[(size_t)row * KP + k0 + c4];
    }
    __syncthreads();
#pragma unroll
    for (int kk = 0; kk < 64; kk += 32) {
      bf16x8 af[4], bfv[4];
#pragma unroll
      for (int m = 0; m < 4; ++m) af[m] = *(const bf16x8*)&As[wrow + m * 16 + lr][kk + hi * 8];
#pragma unroll
      for (int n = 0; n < 4; ++n) bfv[n] = *(const bf16x8*)&Bs[wcol + n * 16 + lr][kk + hi * 8];
#pragma unroll
      for (int m = 0; m < 4; ++m)
#pragma unroll
        for (int n = 0; n < 4; ++n)
          acc[m][n] = __builtin_amdgcn_mfma_f32_16x16x32_bf16(af[m], bfv[n], acc[m][n], 0, 0, 0);
    }
    __syncthreads();
  }

#pragma unroll
  for (int m = 0; m < 4; ++m) {
#pragma unroll
    for (int j = 0; j < 4; ++j) {
      int gr = brow + wrow + m * 16 + hi * 4 + j;
      if (gr >= sg.M) continue;
#pragma unroll
      for (int n = 0; n < 4; ++n) {
        int col = wcol + n * 16 + lr;
        float v = acc[m][n][j] + sg.bias[col];
        Cb[(size_t)(sg.rbase + gr) * 128 + col] = f2b(v);
      }
    }
  }
}

// ---------------- persistent LDS-W wave GEMM (2-tile-pair pipelined): hetero + attproj ----------------
__global__ __launch_bounds__(256) void k_wgemm_het(
    const ushort* __restrict__ A,      // [NTOT][128] bf16
    const ushort* __restrict__ WtH,    // 3 x [128 col][128 k] bf16
    const float* __restrict__ hb,      // [3][128]
    const float* __restrict__ attw,    // [288][4]
    ushort* __restrict__ xh,           // [NTOT][128] bf16
    float* __restrict__ sd, float* __restrict__ ss)
{
  __shared__ ushort Ws[128 * HETP];
  const int tid = threadIdx.x;
  const int bid = blockIdx.x;
  int seg, lb, nb, ntile, segbase, segrows;
  if (bid < 274)      { seg = 0; lb = bid;       nb = 274; ntile = 782;  segbase = 0;           segrows = NGEN; }
  else if (bid < 712) { seg = 1; lb = bid - 274; nb = 438; ntile = 1250; segbase = NGEN;        segrows = NBUS; }
  else                { seg = 2; lb = bid - 712; nb = 56;  ntile = 157;  segbase = NGEN + NBUS; segrows = NRES; }

  const int w = tid >> 6;
  const int lane = tid & 63;
  const int lr = lane & 15, hi = lane >> 4;

  // prologue: load the FIRST PAIR of tiles (lb, lb+nb) before W staging
  int vA, rA, vB, rB;
  {
    int rl = lb * 64 + w * 16;
    vA = rl < segrows; rA = segbase + (vA ? rl : 0);
  }
  {
    int tB = lb + nb;
    if (tB < ntile) {
      int rl = tB * 64 + w * 16;
      vB = rl < segrows; rB = segbase + (vB ? rl : 0);
    } else { vB = 0; rB = segbase; }
  }
  const ushort* ApA = A + (size_t)(rA + lr) * 128 + hi * 8;
  bf16x8 a0 = *(const bf16x8*)(ApA);
  bf16x8 a1 = *(const bf16x8*)(ApA + 32);
  bf16x8 a2 = *(const bf16x8*)(ApA + 64);
  bf16x8 a3 = *(const bf16x8*)(ApA + 96);
  const ushort* ApB = A + (size_t)(rB + lr) * 128 + hi * 8;
  bf16x8 b0 = *(const bf16x8*)(ApB);
  bf16x8 b1 = *(const bf16x8*)(ApB + 32);
  bf16x8 b2 = *(const bf16x8*)(ApB + 64);
  bf16x8 b3 = *(const bf16x8*)(ApB + 96);

  // stage seg W: [128][128] -> padded [128][HETP]
  {
    const ushort* src = WtH + seg * 16384 + tid * 64;
    ushort* dstl = Ws + (tid >> 1) * HETP + (tid & 1) * 64;
#pragma unroll
    for (int j = 0; j < 8; ++j)
      *(u16x8*)&dstl[j * 8] = *(const u16x8*)&src[j * 8];
  }
  __syncthreads();

  const float* bias = hb + seg * 128;
  const ushort* wb0 = Ws + lr * HETP + hi * 8;

  auto do_tile = [&](bf16x8 c0, bf16x8 c1, bf16x8 c2, bf16x8 c3, int currow) {
    f32x4 acc[8];
#pragma unroll
    for (int n = 0; n < 8; ++n) acc[n] = (f32x4){0.f, 0.f, 0.f, 0.f};
#pragma unroll
    for (int n = 0; n < 8; ++n) {
      const ushort* wn = wb0 + n * 16 * HETP;
      acc[n] = __builtin_amdgcn_mfma_f32_16x16x32_bf16(*(const bf16x8*)(wn),      c0, acc[n], 0, 0, 0);
      acc[n] = __builtin_amdgcn_mfma_f32_16x16x32_bf16(*(const bf16x8*)(wn + 32), c1, acc[n], 0, 0, 0);
      acc[n] = __builtin_amdgcn_mfma_f32_16x16x32_bf16(*(const bf16x8*)(wn + 64), c2, acc[n], 0, 0, 0);
      acc[n] = __builtin_amdgcn_mfma_f32_16x16x32_bf16(*(const bf16x8*)(wn + 96), c3, acc[n], 0, 0, 0);
    }
    const int row = currow + lr;
    float pd0 = 0.f, pd1 = 0.f, pd2 = 0.f, pd3 = 0.f;
    float ps0 = 0.f, ps1 = 0.f, ps2 = 0.f, ps3 = 0.f;
#pragma unroll
    for (int n = 0; n < 8; ++n) {
      int c0i = n * 16 + hi * 4;
      float4 bv = *(const float4*)&bias[c0i];
      f32x4 v = acc[n];
      v[0] += bv.x; v[1] += bv.y; v[2] += bv.z; v[3] += bv.w;
      *(ushort4*)&xh[(size_t)row * 128 + c0i] = make_ushort4(f2b(v[0]), f2b(v[1]), f2b(v[2]), f2b(v[3]));
#pragma unroll
      for (int j = 0; j < 4; ++j) {
        float4 wd = *(const float4*)&attw[(c0i + j) * 4];
        float4 ws = *(const float4*)&attw[(128 + c0i + j) * 4];
        pd0 += v[j] * wd.x; pd1 += v[j] * wd.y; pd2 += v[j] * wd.z; pd3 += v[j] * wd.w;
        ps0 += v[j] * ws.x; ps1 += v[j] * ws.y; ps2 += v[j] * ws.z; ps3 += v[j] * ws.w;
      }
    }
    pd0 += __shfl_xor(pd0, 16); pd0 += __shfl_xor(pd0, 32);
    pd1 += __shfl_xor(pd1, 16); pd1 += __shfl_xor(pd1, 32);
    pd2 += __shfl_xor(pd2, 16); pd2 += __shfl_xor(pd2, 32);
    pd3 += __shfl_xor(pd3, 16); pd3 += __shfl_xor(pd3, 32);
    ps0 += __shfl_xor(ps0, 16); ps0 += __shfl_xor(ps0, 32);
    ps1 += __shfl_xor(ps1, 16); ps1 += __shfl_xor(ps1, 32);
    ps2 += __shfl_xor(ps2, 16); ps2 += __shfl_xor(ps2, 32);
    ps3 += __shfl_xor(ps3, 16); ps3 += __shfl_xor(ps3, 32);
    if (hi == 0) {
      float4 o = {pd0, pd1, pd2, pd3};
      *(float4*)&sd[row * 4] = o;
    } else if (hi == 1) {
      float4 o = {ps0, ps1, ps2, ps3};
      *(float4*)&ss[row * 4] = o;
    }
  };

  for (int t = lb; t < ntile; t += 2 * nb) {
    const int cvA = vA, crA = rA, cvB = vB, crB = rB;
    bf16x8 cA0 = a0, cA1 = a1, cA2 = a2, cA3 = a3;
    bf16x8 cB0 = b0, cB1 = b1, cB2 = b2, cB3 = b3;

    // prefetch next pair (t+2nb, t+3nb)
    int tn = t + 2 * nb;
    if (tn < ntile) {
      int rl = tn * 64 + w * 16;
      vA = rl < segrows; rA = segbase + (vA ? rl : 0);
      const ushort* An = A + (size_t)(rA + lr) * 128 + hi * 8;
      a0 = *(const bf16x8*)(An);
      a1 = *(const bf16x8*)(An + 32);
      a2 = *(const bf16x8*)(An + 64);
      a3 = *(const bf16x8*)(An + 96);
      int tn2 = tn + nb;
      if (tn2 < ntile) {
        int rl2 = tn2 * 64 + w * 16;
        vB = rl2 < segrows; rB = segbase + (vB ? rl2 : 0);
        const ushort* Bn = A + (size_t)(rB + lr) * 128 + hi * 8;
        b0 = *(const bf16x8*)(Bn);
        b1 = *(const bf16x8*)(Bn + 32);
        b2 = *(const bf16x8*)(Bn + 64);
        b3 = *(const bf16x8*)(Bn + 96);
      } else vB = 0;
    } else { vA = 0; vB = 0; }

    if (cvA) do_tile(cA0, cA1, cA2, cA3, crA);
    if (cvB) do_tile(cB0, cB1, cB2, cB3, crB);
  }
}

// ---------------- persistent LDS-W wave GEMM (pipelined): linw (K=160), relu + bf16 resid chain ----------------
template<int HASRES, int LAST>
__global__ __launch_bounds__(256) void k_wgemm_lin(
    const ushort* __restrict__ A,      // agg [NTOT][160] bf16 (cols 144.. zero)
    const ushort* __restrict__ Wt,     // [128 col][160 k] bf16 (k 144.. zero)
    const ushort* residb,              // bf16 resid (may alias Cb; row-exclusive)
    float* __restrict__ Cf,            // [NTOT][128] fp32 (LAST)
    ushort* Cb)                        // [NTOT][128] bf16 (!LAST)
{
  __shared__ ushort Ws[128 * LINP];
  const int tid = threadIdx.x;
  const int lane = tid & 63;
  const int lr = lane & 15, hi = lane >> 4;
  const int w = tid >> 6;

  int gw = blockIdx.x * 4 + w;      // < 3072 < NW16 always
  const ushort* Ar0 = A + (size_t)(gw * 16 + lr) * AGGW + hi * 8;
  bf16x8 a0 = *(const bf16x8*)(Ar0);
  bf16x8 a1 = *(const bf16x8*)(Ar0 + 32);
  bf16x8 a2 = *(const bf16x8*)(Ar0 + 64);
  bf16x8 a3 = *(const bf16x8*)(Ar0 + 96);
  bf16x8 a4 = *(const bf16x8*)(Ar0 + 128);

  {
    const ushort* src = Wt + tid * 80;
    ushort* dstl = Ws + (tid >> 1) * LINP + (tid & 1) * 80;
#pragma unroll
    for (int j = 0; j < 10; ++j)
      *(u16x8*)&dstl[j * 8] = *(const u16x8*)&src[j * 8];
  }
  __syncthreads();

  for (; gw < NW16; gw += PGRID * 4) {
    const int gcur = gw;
    bf16x8 c0 = a0, c1 = a1, c2 = a2, c3 = a3, c4 = a4;
    int gn = gw + PGRID * 4;
    if (gn < NW16) {
      const ushort* An = A + (size_t)(gn * 16 + lr) * AGGW + hi * 8;
      a0 = *(const bf16x8*)(An);
      a1 = *(const bf16x8*)(An + 32);
      a2 = *(const bf16x8*)(An + 64);
      a3 = *(const bf16x8*)(An + 96);
      a4 = *(const bf16x8*)(An + 128);
    }

    f32x4 acc[8];
#pragma unroll
    for (int n = 0; n < 8; ++n) acc[n] = (f32x4){0.f, 0.f, 0.f, 0.f};
    const ushort* wb0 = Ws + lr * LINP + hi * 8;
#pragma unroll
    for (int n = 0; n < 8; ++n) {
      const ushort* wn = wb0 + n * 16 * LINP;
      acc[n] = __builtin_amdgcn_mfma_f32_16x16x32_bf16(*(const bf16x8*)(wn),       c0, acc[n], 0, 0, 0);
      acc[n] = __builtin_amdgcn_mfma_f32_16x16x32_bf16(*(const bf16x8*)(wn + 32),  c1, acc[n], 0, 0, 0);
      acc[n] = __builtin_amdgcn_mfma_f32_16x16x32_bf16(*(const bf16x8*)(wn + 64),  c2, acc[n], 0, 0, 0);
      acc[n] = __builtin_amdgcn_mfma_f32_16x16x32_bf16(*(const bf16x8*)(wn + 96),  c3, acc[n], 0, 0, 0);
      acc[n] = __builtin_amdgcn_mfma_f32_16x16x32_bf16(*(const bf16x8*)(wn + 128), c4, acc[n], 0, 0, 0);
    }

    const int row = gcur * 16 + lr;
#pragma unroll
    for (int n = 0; n < 8; ++n) {
      int c0i = n * 16 + hi * 4;
      f32x4 v = acc[n];
      v[0] = fmaxf(v[0], 0.f); v[1] = fmaxf(v[1], 0.f);
      v[2] = fmaxf(v[2], 0.f); v[3] = fmaxf(v[3], 0.f);
      if (HASRES) {
        ushort4 r = *(const ushort4*)&residb[(size_t)row * 128 + c0i];
        v[0] += b2f(r.x); v[1] += b2f(r.y); v[2] += b2f(r.z); v[3] += b2f(r.w);
      }
      if (LAST) {
        *(f32x4*)&Cf[(size_t)row * 128 + c0i] = v;
      } else {
        *(ushort4*)&Cb[(size_t)row * 128 + c0i] =
            make_ushort4(f2b(v[0]), f2b(v[1]), f2b(v[2]), f2b(v[3]));
      }
    }
  }
}

// ---------------- per-edge: eaee + logits, written at CSR position ----------------
__global__ __launch_bounds__(256) void k_edge(
    const int* __restrict__ esrc, const int* __restrict__ edst,
    const int* __restrict__ epos,
    const float* __restrict__ ea_all, const float* __restrict__ eae,
    const float* __restrict__ attw, const float* __restrict__ ete,
    const float* __restrict__ sd, const float* __restrict__ ss,
    ushort* __restrict__ eaeeB, float* __restrict__ a4buf)
{
  __shared__ float tc[4][4];
  if (threadIdx.x < 16) {
    int tt = threadIdx.x >> 2, h = threadIdx.x & 3;
    float s = 0.f;
    for (int j = 0; j < 16; ++j) s += lrelu(ete[tt * 16 + j]) * attw[(256 + j) * 4 + h];
    tc[tt][h] = s;
  }
  __syncthreads();

  int e = blockIdx.x * 256 + threadIdx.x;
  if (e >= ETOT) return;
  int t = (e < EPROD) ? 0 : (e < EPROD + ESERV) ? 1 : (e < EPROD + ESERV + ETRAN) ? 2 : 3;
  float a0 = ea_all[2 * e], a1 = ea_all[2 * e + 1];
  int s = esrc[e], d = edst[e];
  int pos = epos[e];
  float4 sdv = *(const float4*)&sd[d * 4];
  float4 ssv = *(const float4*)&ss[s * 4];
  float acc[4] = {sdv.x + ssv.x + tc[t][0], sdv.y + ssv.y + tc[t][1],
                  sdv.z + ssv.z + tc[t][2], sdv.w + ssv.w + tc[t][3]};
  ushort us[16];
#pragma unroll
  for (int j = 0; j < 16; ++j) {
    float v = lrelu(a0 * eae[j] + a1 * eae[16 + j]);
    us[j] = f2b(v);
    float4 aw = *(const float4*)&attw[(272 + j) * 4];
    acc[0] += v * aw.x; acc[1] += v * aw.y; acc[2] += v * aw.z; acc[3] += v * aw.w;
  }
  *(ushort4*)&eaeeB[(size_t)pos * 16 + 0]  = make_ushort4(us[0], us[1], us[2], us[3]);
  *(ushort4*)&eaeeB[(size_t)pos * 16 + 4]  = make_ushort4(us[4], us[5], us[6], us[7]);
  *(ushort4*)&eaeeB[(size_t)pos * 16 + 8]  = make_ushort4(us[8], us[9], us[10], us[11]);
  *(ushort4*)&eaeeB[(size_t)pos * 16 + 12] = make_ushort4(us[12], us[13], us[14], us[15]);
  float4 out = {lrelu(acc[0]), lrelu(acc[1]), lrelu(acc[2]), lrelu(acc[3])};
  *(float4*)&a4buf[(size_t)pos * 4] = out;
}

// ---------------- per-node softmax: contiguous CSR reads ----------------
__global__ __launch_bounds__(256) void k_softmax(
    const int* __restrict__ rp,
    const float* __restrict__ a4buf, float* __restrict__ ab)
{
  int n = blockIdx.x * 256 + threadIdx.x;
  if (n >= NTOT) return;
  int beg = rp[n], end = rp[n + 1];
  if (beg == end) return;
  float m0 = -INFINITY, m1 = -INFINITY, m2 = -INFINITY, m3 = -INFINITY;
  for (int i = beg; i < end; ++i) {
    float4 av = *(const float4*)&a4buf[(size_t)i * 4];
    m0 = fmaxf(m0, av.x); m1 = fmaxf(m1, av.y); m2 = fmaxf(m2, av.z); m3 = fmaxf(m3, av.w);
  }
  float d0 = 0.f, d1 = 0.f, d2 = 0.f, d3 = 0.f;
  for (int i = beg; i < end; ++i) {
    float4 av = *(const float4*)&a4buf[(size_t)i * 4];
    d0 += __expf(av.x - m0); d1 += __expf(av.y - m1);
    d2 += __expf(av.z - m2); d3 += __expf(av.w - m3);
  }
  d0 = 1.f / (d0 + 1e-16f); d1 = 1.f / (d1 + 1e-16f);
  d2 = 1.f / (d2 + 1e-16f); d3 = 1.f / (d3 + 1e-16f);
  for (int i = beg; i < end; ++i) {
    float4 av = *(const float4*)&a4buf[(size_t)i * 4];
    ab[i] = 0.25f * (__expf(av.x - m0) * d0 + __expf(av.y - m1) * d1 +
                     __expf(av.z - m2) * d2 + __expf(av.w - m3) * d3);
  }
}

// ---------------- per-dst weighted gather: all CSR-side reads contiguous ----------------
__global__ __launch_bounds__(256) void k_gather(
    const int* __restrict__ rp, const int* __restrict__ srcp,
    const float* __restrict__ ab, const ushort* __restrict__ eaeeB,
    const ushort* __restrict__ xh, ushort* __restrict__ agg)
{
  int wid = (blockIdx.x * 256 + threadIdx.x) >> 6;
  int lane = threadIdx.x & 63;
  if (wid >= NTOT) return;
  int beg = rp[wid], end = rp[wid + 1];
  int deg = end - beg;
  const int l2 = lane & 31;
  const int half = lane >> 5;
  size_t rb = (size_t)wid * AGGW;

  if (deg == 0) {
    *(ushort2*)&agg[rb + lane * 2] = make_ushort2(0, 0);
    if (lane < 16) *(ushort2*)&agg[rb + 128 + lane * 2] = make_ushort2(0, 0);
    return;
  }

  f32x4 axv = (f32x4){0.f, 0.f, 0.f, 0.f};
  float ae0 = 0.f, ae1 = 0.f;

  if (deg <= 64) {
    int sj = 0; float wj = 0.f;
    if (lane < deg) {
      sj = srcp[beg + lane];
      wj = ab[beg + lane];
    }
    for (int j0 = 0; j0 < deg; j0 += 2) {
      int j = j0 + half;
      bool jv = j < deg;
      int jj = jv ? j : 0;
      float wab = jv ? __shfl(wj, jj) : 0.f;
      int s = __shfl(sj, jj);
      ushort4 xv = *(const ushort4*)&xh[(size_t)s * 128 + l2 * 4];
      axv[0] += wab * b2f(xv.x); axv[1] += wab * b2f(xv.y);
      axv[2] += wab * b2f(xv.z); axv[3] += wab * b2f(xv.w);
      if (l2 < 8) {
        ushort2 q = *(const ushort2*)&eaeeB[(size_t)(beg + jj) * 16 + l2 * 2];
        ae0 += wab * b2f(q.x); ae1 += wab * b2f(q.y);
      }
    }
  } else {
    for (int i = beg; i < end; i += 2) {
      int idx = i + half;
      bool valid = idx < end;
      int idc = valid ? idx : beg;
      int s = srcp[idc];
      float w = valid ? ab[idc] : 0.f;
      ushort4 xv = *(const ushort4*)&xh[(size_t)s * 128 + l2 * 4];
      axv[0] += w * b2f(xv.x); axv[1] += w * b2f(xv.y);
      axv[2] += w * b2f(xv.z); axv[3] += w * b2f(xv.w);
      if (l2 < 8) {
        ushort2 q = *(const ushort2*)&eaeeB[(size_t)idc * 16 + l2 * 2];
        ae0 += w * b2f(q.x); ae1 += w * b2f(q.y);
      }
    }
  }
#pragma unroll
  for (int j = 0; j < 4; ++j) axv[j] += __shfl_xor(axv[j], 32);
  ae0 += __shfl_xor(ae0, 32); ae1 += __shfl_xor(ae1, 32);

  if (half == 0) {
    *(ushort4*)&agg[rb + l2 * 4] =
        make_ushort4(f2b(axv[0]), f2b(axv[1]), f2b(axv[2]), f2b(axv[3]));
  } else {
    if (l2 < 8) *(ushort2*)&agg[rb + 128 + l2 * 2] = make_ushort2(f2b(ae0), f2b(ae1));
    else if (l2 < 16) *(ushort2*)&agg[rb + 144 + (l2 - 8) * 2] = make_ushort2(0, 0);
  }
}

// ---------------- launch ----------------
extern "C" void kernel_launch(void* const* d_in, const int* in_sizes, int n_in,
                              void* d_out, int out_size, void* d_ws, size_t ws_size,
                              hipStream_t stream)
{
  const float* x_gen = (const float*)d_in[0];
  const float* x_bus = (const float*)d_in[1];
  const float* x_res = (const float*)d_in[2];
  const int* eip = (const int*)d_in[3];
  const int* eis = (const int*)d_in[4];
  const int* eit = (const int*)d_in[5];
  const int* eib = (const int*)d_in[6];
  const float* eap = (const float*)d_in[7];
  const float* eas = (const float*)d_in[8];
  const float* eat = (const float*)d_in[9];
  const float* eab = (const float*)d_in[10];
  const float* pW_gen = (const float*)d_in[11];
  const float* pb_gen = (const float*)d_in[12];
  const float* pW_bus = (const float*)d_in[13];
  const float* pb_bus = (const float*)d_in[14];
  const float* pW_res = (const float*)d_in[15];
  const float* pb_res = (const float*)d_in[16];

  float* out = (float*)d_out;

  char* p = (char*)d_ws;
  auto alloc = [&](size_t bytes) -> void* {
    void* r = (void*)p;
    p += (bytes + 255) & ~(size_t)255;
    return r;
  };
  int* esrc    = (int*)alloc((size_t)ETOT * 4);
  int* edst    = (int*)alloc((size_t)ETOT * 4);
  float* ea_all = (float*)alloc((size_t)ETOT * 2 * 4);
  int* cnt     = (int*)alloc((size_t)NTOT * 4);
  int* fill    = (int*)alloc((size_t)NTOT * 4);
  int* rp      = (int*)alloc((size_t)(NTOT + 1) * 4);
  int* bsum    = (int*)alloc(1024 * 4);
  int* srcp    = (int*)alloc((size_t)ETOT * 4);
  int* epos    = (int*)alloc((size_t)ETOT * 4);
  float* ab    = (float*)alloc((size_t)ETOT * 4);
  ushort* Wt   = (ushort*)alloc((size_t)233472 * 2);
  ushort* x_bf = (ushort*)alloc((size_t)NTOT * HID * 2);   // activation chain (bf16)
  ushort* xh_bf = (ushort*)alloc((size_t)NTOT * HID * 2);
  float* sd    = (float*)alloc((size_t)NTOT * 4 * 4);
  float* ss    = (float*)alloc((size_t)NTOT * 4 * 4);
  ushort* eaeeB = (ushort*)alloc((size_t)ETOT * 16 * 2);
  float* a4buf = (float*)alloc((size_t)ETOT * 4 * 4);
  ushort* agg  = (ushort*)alloc((size_t)NTOT * AGGW * 2);

  // ---- CSR build ----
  hipMemsetAsync(cnt, 0, (size_t)NTOT * 4, stream);
  hipMemsetAsync(fill, 0, (size_t)NTOT * 4, stream);
  k_setup_edges<<<EB, 256, 0, stream>>>(eip, eis, eit, eib, eap, eas, eat, eab, esrc, edst, ea_all, cnt);
  k_scan1<<<NB_SCAN, 256, 0, stream>>>(cnt, rp, bsum);
  k_scan2<<<1, 1024, 0, stream>>>(bsum, NB_SCAN);
  k_scan3<<<NB_SCAN, 256, 0, stream>>>(rp, bsum);
  k_scatter<<<EB, 256, 0, stream>>>(esrc, edst, rp, fill, srcp, epos);

  // ---- weight conversion ----
  k_convW<<<912, 256, 0, stream>>>(pW_gen, pW_bus, pW_res,
      (const float*)d_in[17], (const float*)d_in[22],
      (const float*)d_in[23], (const float*)d_in[28],
      (const float*)d_in[29], (const float*)d_in[34], Wt);

  const int NB0 = (NGEN + 127) / 128, NB1 = (NBUS + 127) / 128, NB2 = (NRES + 127) / 128;
  const int NBT = NB0 + NB1 + NB2;

  // ---- input projections -> x_bf ----
  {
    Seg s0{x_gen, Wt + 0,     pb_gen, 39, 39, NGEN, NB0, 0};
    Seg s1{x_bus, Wt + 8192,  pb_bus, 16, 16, NBUS, NB1, NGEN};
    Seg s2{x_res, Wt + 16384, pb_res, 16, 16, NRES, NB2, NGEN + NBUS};
    k_mgemm3<<<NBT, 256, 0, stream>>>(s0, s1, s2, 64, x_bf);
  }

  for (int l = 0; l < 3; ++l) {
    const float* hb   = (const float*)d_in[18 + l * 6];
    const float* ete  = (const float*)d_in[19 + l * 6];
    const float* eae  = (const float*)d_in[20 + l * 6];
    const float* attw = (const float*)d_in[21 + l * 6];
    const ushort* WtH = Wt + 24576 + l * 69632;
    const ushort* WtL = Wt + 24576 + l * 69632 + 49152;

    // HeteroLinear + fused attention projections (persistent LDS-W, 2-tile-pair pipelined)
    k_wgemm_het<<<PGRID, 256, 0, stream>>>(x_bf, WtH, hb, attw, xh_bf, sd, ss);

    k_edge<<<EB, 256, 0, stream>>>(esrc, edst, epos, ea_all, eae, attw, ete, sd, ss, eaeeB, a4buf);
    k_softmax<<<NB_SCAN, 256, 0, stream>>>(rp, a4buf, ab);
    k_gather<<<WB, 256, 0, stream>>>(rp, srcp, ab, eaeeB, xh_bf, agg);

    // x_{l+1} = relu(agg @ linw) + x_l  (bf16 chain; final layer -> fp32 out)
    if (l == 0)      k_wgemm_lin<0,0><<<PGRID, 256, 0, stream>>>(agg, WtL, nullptr, nullptr, x_bf);
    else if (l == 1) k_wgemm_lin<1,0><<<PGRID, 256, 0, stream>>>(agg, WtL, x_bf, nullptr, x_bf);
    else             k_wgemm_lin<1,1><<<PGRID, 256, 0, stream>>>(agg, WtL, x_bf, out, nullptr);
  }
}

// Round 18
// 535.905 us; speedup vs baseline: 1.0521x; 1.0521x over previous
//
#include <hip/hip_runtime.h>
#include <hip/hip_bf16.h>

#define NGEN 50000
#define NBUS 80000
#define NRES 10000
#define NTOT 140000
#define EPROD 100000
#define ESERV 100000
#define ETRAN 150000
#define EBACK 50000
#define ETOT  400000
#define HID 128
#define NEGS 0.2f

#define NB_SCAN 547   // ceil(NTOT/256)
#define EB 1563       // ceil(ETOT/256)
#define WB 35000      // NTOT waves of 64 in 256-thread blocks
#define NW16 8750     // NTOT/16 row-groups
#define PGRID 768     // persistent blocks (3/CU) — 1024 regressed twice (R9, R15)
#define AGGW 160      // agg row width (144 real + 16 pad)
#define LINP 172      // padded LDS row for K=160
#define HETP 140      // padded LDS row for K=128

typedef __attribute__((ext_vector_type(8))) short bf16x8;
typedef __attribute__((ext_vector_type(8))) unsigned short u16x8;
typedef __attribute__((ext_vector_type(4))) float f32x4;

__device__ __forceinline__ float lrelu(float x) { return x >= 0.f ? x : NEGS * x; }
__device__ __forceinline__ float b2f(ushort u) { union { float f; uint i; } v; v.i = (uint)u << 16; return v.f; }
__device__ __forceinline__ ushort f2b(float f) {
  union { float f; uint i; } v; v.f = f;
  return (ushort)((v.i + 0x7FFF + ((v.i >> 16) & 1)) >> 16);
}

// ---------------- edge setup (+ degree count) ----------------
__global__ __launch_bounds__(256) void k_setup_edges(
    const int* __restrict__ eip, const int* __restrict__ eis,
    const int* __restrict__ eit, const int* __restrict__ eib,
    const float* __restrict__ eap, const float* __restrict__ eas,
    const float* __restrict__ eat, const float* __restrict__ eab,
    int* __restrict__ esrc, int* __restrict__ edst, float* __restrict__ ea_all,
    int* __restrict__ cnt)
{
  int e = blockIdx.x * 256 + threadIdx.x;
  if (e >= ETOT) return;
  int s, d; float a0, a1;
  if (e < EPROD) { s = eip[e]; d = eip[EPROD + e]; a0 = eap[2*e]; a1 = eap[2*e+1]; }
  else if (e < EPROD+ESERV) { int i = e - EPROD; s = eis[i]; d = eis[ESERV + i]; a0 = eas[2*i]; a1 = eas[2*i+1]; }
  else if (e < EPROD+ESERV+ETRAN) { int i = e - EPROD - ESERV; s = eit[i]; d = eit[ETRAN + i]; a0 = eat[2*i]; a1 = eat[2*i+1]; }
  else { int i = e - EPROD - ESERV - ETRAN; s = eib[i]; d = eib[EBACK + i]; a0 = eab[2*i]; a1 = eab[2*i+1]; }
  esrc[e] = s; edst[e] = d; ea_all[2*e] = a0; ea_all[2*e+1] = a1;
  atomicAdd(&cnt[d], 1);
}

// hierarchical scan
__global__ __launch_bounds__(256) void k_scan1(const int* __restrict__ cnt,
                                               int* __restrict__ rp, int* __restrict__ bsum)
{
  int t = threadIdx.x, i = blockIdx.x * 256 + t;
  int v = (i < NTOT) ? cnt[i] : 0;
  __shared__ int buf[256];
  buf[t] = v; __syncthreads();
  for (int off = 1; off < 256; off <<= 1) {
    int x = (t >= off) ? buf[t - off] : 0;
    __syncthreads(); buf[t] += x; __syncthreads();
  }
  if (i < NTOT) rp[i] = buf[t] - v;
  if (t == 255) bsum[blockIdx.x] = buf[255];
}

__global__ __launch_bounds__(1024) void k_scan2(int* __restrict__ bsum, int nb)
{
  int t = threadIdx.x;
  __shared__ int buf[1024];
  int v = (t < nb) ? bsum[t] : 0;
  buf[t] = v; __syncthreads();
  for (int off = 1; off < 1024; off <<= 1) {
    int x = (t >= off) ? buf[t - off] : 0;
    __syncthreads(); buf[t] += x; __syncthreads();
  }
  if (t < nb) bsum[t] = buf[t] - v;
}

__global__ __launch_bounds__(256) void k_scan3(int* __restrict__ rp, const int* __restrict__ bsum)
{
  int i = blockIdx.x * 256 + threadIdx.x;
  if (i < NTOT) rp[i] += bsum[blockIdx.x];
  if (i == 0) rp[NTOT] = ETOT;
}

// scatter: srcp[pos] = src node; epos[e] = CSR position of edge e
__global__ __launch_bounds__(256) void k_scatter(const int* __restrict__ esrc,
    const int* __restrict__ edst, const int* __restrict__ rp,
    int* __restrict__ fill, int* __restrict__ srcp, int* __restrict__ epos)
{
  int e = blockIdx.x * 256 + threadIdx.x;
  if (e >= ETOT) return;
  int d = edst[e];
  int pos = rp[d] + atomicAdd(&fill[d], 1);
  srcp[pos] = esrc[e];
  epos[e] = pos;
}

// ---------------- weight conversion ----------------
__global__ __launch_bounds__(256) void k_convW(
    const float* __restrict__ pg, const float* __restrict__ pb, const float* __restrict__ pr,
    const float* __restrict__ h1, const float* __restrict__ l1,
    const float* __restrict__ h2, const float* __restrict__ l2,
    const float* __restrict__ h3, const float* __restrict__ l3,
    ushort* __restrict__ dst)
{
  int idx = blockIdx.x * 256 + threadIdx.x;
  if (idx >= 233472) return;
  const float* src; int K, KP, base;
  if (idx < 24576) {
    int s = idx >> 13;
    src = (s == 0) ? pg : (s == 1) ? pb : pr;
    K = (s == 0) ? 39 : 16; KP = 64; base = s * 8192;
  } else {
    int r = idx - 24576, l = r / 69632, q = r % 69632;
    const float* h = (l == 0) ? h1 : (l == 1) ? h2 : h3;
    const float* lw = (l == 0) ? l1 : (l == 1) ? l2 : l3;
    if (q < 49152) { int t = q >> 14; src = h + t * 16384; K = 128; KP = 128; base = 24576 + l * 69632 + t * 16384; }
    else { src = lw; K = 144; KP = 160; base = 24576 + l * 69632 + 49152; }
  }
  int li = idx - base, c = li / KP, k = li % KP;
  dst[idx] = (k < K) ? f2b(src[k * 128 + c]) : (ushort)0;
}

// ---------------- segmented LDS GEMM (input projections only, K<=39) ----------------
struct Seg {
  const void* A; const ushort* Wt; const float* bias;
  int lda, K, M, nb, rbase;
};

__global__ __launch_bounds__(256) void k_mgemm3(Seg s0, Seg s1, Seg s2, int KP, ushort* __restrict__ Cb)
{
  __shared__ ushort As[128][72];
  __shared__ ushort Bs[128][72];
  int bid = blockIdx.x;
  Seg sg = s0;
  if (bid >= s0.nb + s1.nb) { sg = s2; bid -= s0.nb + s1.nb; }
  else if (bid >= s0.nb) { sg = s1; bid -= s0.nb; }

  const int tid = threadIdx.x;
  const int lr = tid & 15, hi = (tid & 63) >> 4;
  const int w = tid >> 6;
  const int wrow = (w >> 1) * 64, wcol = (w & 1) * 64;
  const int brow = bid * 128;

  f32x4 acc[4][4];
#pragma unroll
  for (int m = 0; m < 4; ++m)
#pragma unroll
    for (int n = 0; n < 4; ++n) acc[m][n] = (f32x4){0.f, 0.f, 0.f, 0.f};

  for (int k0 = 0; k0 < KP; k0 += 64) {
#pragma unroll
    for (int p = 0; p < 8; ++p) {
      int li = tid + 256 * p;
      int row = li >> 4, c4 = (li & 15) * 4;
      int gr = brow + row, gk = k0 + c4;
      ushort4 u = make_ushort4(0, 0, 0, 0);
      if (gr < sg.M) {
        const float* A = (const float*)sg.A;
        const float* ar = A + (size_t)gr * sg.lda;
        if (gk + 0 < sg.K) u.x = f2b(ar[gk + 0]);
        if (gk + 1 < sg.K) u.y = f2b(ar[gk + 1]);
        if (gk + 2 < sg.K) u.z = f2b(ar[gk + 2]);
        if (gk + 3 < sg.K) u.w = f2b(ar[gk + 3]);
      }
      *(ushort4*)&As[row][c4] = u;
    }
#pragma unroll
    for (int p = 0; p < 8; ++p) {
      int li = tid + 256 * p;
      int row = li >> 4, c4 = (li & 15) * 4;
      *(ushort4*)&Bs[row][c4] = *(const ushort4*)&sg.Wt[(size_t)row * KP + k0 + c4];
    }
    __syncthreads();
#pragma unroll
    for (int kk = 0; kk < 64; kk += 32) {
      bf16x8 af[4], bfv[4];
#pragma unroll
      for (int m = 0; m < 4; ++m) af[m] = *(const bf16x8*)&As[wrow + m * 16 + lr][kk + hi * 8];
#pragma unroll
      for (int n = 0; n < 4; ++n) bfv[n] = *(const bf16x8*)&Bs[wcol + n * 16 + lr][kk + hi * 8];
#pragma unroll
      for (int m = 0; m < 4; ++m)
#pragma unroll
        for (int n = 0; n < 4; ++n)
          acc[m][n] = __builtin_amdgcn_mfma_f32_16x16x32_bf16(af[m], bfv[n], acc[m][n], 0, 0, 0);
    }
    __syncthreads();
  }

#pragma unroll
  for (int m = 0; m < 4; ++m) {
#pragma unroll
    for (int j = 0; j < 4; ++j) {
      int gr = brow + wrow + m * 16 + hi * 4 + j;
      if (gr >= sg.M) continue;
#pragma unroll
      for (int n = 0; n < 4; ++n) {
        int col = wcol + n * 16 + lr;
        float v = acc[m][n][j] + sg.bias[col];
        Cb[(size_t)(sg.rbase + gr) * 128 + col] = f2b(v);
      }
    }
  }
}

// ---------------- persistent LDS-W wave GEMM (A-pipelined, coalesced xh store): hetero + attproj ----------------
__global__ __launch_bounds__(256) void k_wgemm_het(
    const ushort* __restrict__ A,      // [NTOT][128] bf16
    const ushort* __restrict__ WtH,    // 3 x [128 col][128 k] bf16
    const float* __restrict__ hb,      // [3][128]
    const float* __restrict__ attw,    // [288][4]
    ushort* __restrict__ xh,           // [NTOT][128] bf16
    float* __restrict__ sd, float* __restrict__ ss)
{
  __shared__ ushort Ws[128 * HETP];
  __shared__ ushort Xb[4][16][136];    // wave-private xh staging (padded; 17 KB)
  const int tid = threadIdx.x;
  const int bid = blockIdx.x;
  int seg, lb, nb, ntile, segbase, segrows;
  if (bid < 274)      { seg = 0; lb = bid;       nb = 274; ntile = 782;  segbase = 0;           segrows = NGEN; }
  else if (bid < 712) { seg = 1; lb = bid - 274; nb = 438; ntile = 1250; segbase = NGEN;        segrows = NBUS; }
  else                { seg = 2; lb = bid - 712; nb = 56;  ntile = 157;  segbase = NGEN + NBUS; segrows = NRES; }

  const int w = tid >> 6;
  const int lane = tid & 63;
  const int lr = lane & 15, hi = lane >> 4;

  // prologue: issue tile lb's A-loads BEFORE staging (latency hides under staging+barrier)
  int rl = lb * 64 + w * 16;
  int valid = rl < segrows;
  int r0 = segbase + (valid ? rl : 0);
  const ushort* Ap = A + (size_t)(r0 + lr) * 128 + hi * 8;
  bf16x8 a0 = *(const bf16x8*)(Ap);
  bf16x8 a1 = *(const bf16x8*)(Ap + 32);
  bf16x8 a2 = *(const bf16x8*)(Ap + 64);
  bf16x8 a3 = *(const bf16x8*)(Ap + 96);

  // stage seg W: [128][128] -> padded [128][HETP]
  {
    const ushort* src = WtH + seg * 16384 + tid * 64;
    ushort* dstl = Ws + (tid >> 1) * HETP + (tid & 1) * 64;
#pragma unroll
    for (int j = 0; j < 8; ++j)
      *(u16x8*)&dstl[j * 8] = *(const u16x8*)&src[j * 8];
  }
  __syncthreads();

  const float* bias = hb + seg * 128;

  for (int t = lb; t < ntile; t += nb) {
    const int curvalid = valid, currow = r0;
    bf16x8 c0 = a0, c1 = a1, c2 = a2, c3 = a3;

    int tn = t + nb;
    if (tn < ntile) {
      rl = tn * 64 + w * 16;
      valid = rl < segrows;
      r0 = segbase + (valid ? rl : 0);
      const ushort* An = A + (size_t)(r0 + lr) * 128 + hi * 8;
      a0 = *(const bf16x8*)(An);
      a1 = *(const bf16x8*)(An + 32);
      a2 = *(const bf16x8*)(An + 64);
      a3 = *(const bf16x8*)(An + 96);
    }
    if (!curvalid) continue;

    f32x4 acc[8];
#pragma unroll
    for (int n = 0; n < 8; ++n) acc[n] = (f32x4){0.f, 0.f, 0.f, 0.f};
    const ushort* wb0 = Ws + lr * HETP + hi * 8;
#pragma unroll
    for (int n = 0; n < 8; ++n) {
      const ushort* wn = wb0 + n * 16 * HETP;
      acc[n] = __builtin_amdgcn_mfma_f32_16x16x32_bf16(*(const bf16x8*)(wn),      c0, acc[n], 0, 0, 0);
      acc[n] = __builtin_amdgcn_mfma_f32_16x16x32_bf16(*(const bf16x8*)(wn + 32), c1, acc[n], 0, 0, 0);
      acc[n] = __builtin_amdgcn_mfma_f32_16x16x32_bf16(*(const bf16x8*)(wn + 64), c2, acc[n], 0, 0, 0);
      acc[n] = __builtin_amdgcn_mfma_f32_16x16x32_bf16(*(const bf16x8*)(wn + 96), c3, acc[n], 0, 0, 0);
    }

    float pd0 = 0.f, pd1 = 0.f, pd2 = 0.f, pd3 = 0.f;
    float ps0 = 0.f, ps1 = 0.f, ps2 = 0.f, ps3 = 0.f;
#pragma unroll
    for (int n = 0; n < 8; ++n) {
      int c0i = n * 16 + hi * 4;
      float4 bv = *(const float4*)&bias[c0i];
      f32x4 v = acc[n];
      v[0] += bv.x; v[1] += bv.y; v[2] += bv.z; v[3] += bv.w;
      *(ushort4*)&Xb[w][lr][c0i] = make_ushort4(f2b(v[0]), f2b(v[1]), f2b(v[2]), f2b(v[3]));
#pragma unroll
      for (int j = 0; j < 4; ++j) {
        float4 wd = *(const float4*)&attw[(c0i + j) * 4];
        float4 ws = *(const float4*)&attw[(128 + c0i + j) * 4];
        pd0 += v[j] * wd.x; pd1 += v[j] * wd.y; pd2 += v[j] * wd.z; pd3 += v[j] * wd.w;
        ps0 += v[j] * ws.x; ps1 += v[j] * ws.y; ps2 += v[j] * ws.z; ps3 += v[j] * ws.w;
      }
    }
    // coalesced xh store: 4 x 1KB contiguous (rows currow..currow+15)
#pragma unroll
    for (int k4 = 0; k4 < 4; ++k4) {
      int rrow = k4 * 4 + hi;
      int ccol = lr * 8;
      u16x8 val = *(const u16x8*)&Xb[w][rrow][ccol];
      *(u16x8*)&xh[(size_t)(currow + rrow) * 128 + ccol] = val;
    }
    const int row = currow + lr;
    pd0 += __shfl_xor(pd0, 16); pd0 += __shfl_xor(pd0, 32);
    pd1 += __shfl_xor(pd1, 16); pd1 += __shfl_xor(pd1, 32);
    pd2 += __shfl_xor(pd2, 16); pd2 += __shfl_xor(pd2, 32);
    pd3 += __shfl_xor(pd3, 16); pd3 += __shfl_xor(pd3, 32);
    ps0 += __shfl_xor(ps0, 16); ps0 += __shfl_xor(ps0, 32);
    ps1 += __shfl_xor(ps1, 16); ps1 += __shfl_xor(ps1, 32);
    ps2 += __shfl_xor(ps2, 16); ps2 += __shfl_xor(ps2, 32);
    ps3 += __shfl_xor(ps3, 16); ps3 += __shfl_xor(ps3, 32);
    if (hi == 0) {
      float4 o = {pd0, pd1, pd2, pd3};
      *(float4*)&sd[row * 4] = o;
    } else if (hi == 1) {
      float4 o = {ps0, ps1, ps2, ps3};
      *(float4*)&ss[row * 4] = o;
    }
  }
}

// ---------------- persistent LDS-W wave GEMM (pipelined): linw (K=160), relu + bf16 resid chain ----------------
template<int HASRES, int LAST>
__global__ __launch_bounds__(256) void k_wgemm_lin(
    const ushort* __restrict__ A,      // agg [NTOT][160] bf16 (cols 144.. zero)
    const ushort* __restrict__ Wt,     // [128 col][160 k] bf16 (k 144.. zero)
    const ushort* residb,              // bf16 resid (may alias Cb; row-exclusive)
    float* __restrict__ Cf,            // [NTOT][128] fp32 (LAST)
    ushort* Cb)                        // [NTOT][128] bf16 (!LAST)
{
  __shared__ ushort Ws[128 * LINP];
  const int tid = threadIdx.x;
  const int lane = tid & 63;
  const int lr = lane & 15, hi = lane >> 4;
  const int w = tid >> 6;

  int gw = blockIdx.x * 4 + w;      // < 3072 < NW16 always
  const ushort* Ar0 = A + (size_t)(gw * 16 + lr) * AGGW + hi * 8;
  bf16x8 a0 = *(const bf16x8*)(Ar0);
  bf16x8 a1 = *(const bf16x8*)(Ar0 + 32);
  bf16x8 a2 = *(const bf16x8*)(Ar0 + 64);
  bf16x8 a3 = *(const bf16x8*)(Ar0 + 96);
  bf16x8 a4 = *(const bf16x8*)(Ar0 + 128);

  {
    const ushort* src = Wt + tid * 80;
    ushort* dstl = Ws + (tid >> 1) * LINP + (tid & 1) * 80;
#pragma unroll
    for (int j = 0; j < 10; ++j)
      *(u16x8*)&dstl[j * 8] = *(const u16x8*)&src[j * 8];
  }
  __syncthreads();

  for (; gw < NW16; gw += PGRID * 4) {
    const int gcur = gw;
    bf16x8 c0 = a0, c1 = a1, c2 = a2, c3 = a3, c4 = a4;
    int gn = gw + PGRID * 4;
    if (gn < NW16) {
      const ushort* An = A + (size_t)(gn * 16 + lr) * AGGW + hi * 8;
      a0 = *(const bf16x8*)(An);
      a1 = *(const bf16x8*)(An + 32);
      a2 = *(const bf16x8*)(An + 64);
      a3 = *(const bf16x8*)(An + 96);
      a4 = *(const bf16x8*)(An + 128);
    }

    f32x4 acc[8];
#pragma unroll
    for (int n = 0; n < 8; ++n) acc[n] = (f32x4){0.f, 0.f, 0.f, 0.f};
    const ushort* wb0 = Ws + lr * LINP + hi * 8;
#pragma unroll
    for (int n = 0; n < 8; ++n) {
      const ushort* wn = wb0 + n * 16 * LINP;
      acc[n] = __builtin_amdgcn_mfma_f32_16x16x32_bf16(*(const bf16x8*)(wn),       c0, acc[n], 0, 0, 0);
      acc[n] = __builtin_amdgcn_mfma_f32_16x16x32_bf16(*(const bf16x8*)(wn + 32),  c1, acc[n], 0, 0, 0);
      acc[n] = __builtin_amdgcn_mfma_f32_16x16x32_bf16(*(const bf16x8*)(wn + 64),  c2, acc[n], 0, 0, 0);
      acc[n] = __builtin_amdgcn_mfma_f32_16x16x32_bf16(*(const bf16x8*)(wn + 96),  c3, acc[n], 0, 0, 0);
      acc[n] = __builtin_amdgcn_mfma_f32_16x16x32_bf16(*(const bf16x8*)(wn + 128), c4, acc[n], 0, 0, 0);
    }

    const int row = gcur * 16 + lr;
#pragma unroll
    for (int n = 0; n < 8; ++n) {
      int c0i = n * 16 + hi * 4;
      f32x4 v = acc[n];
      v[0] = fmaxf(v[0], 0.f); v[1] = fmaxf(v[1], 0.f);
      v[2] = fmaxf(v[2], 0.f); v[3] = fmaxf(v[3], 0.f);
      if (HASRES) {
        ushort4 r = *(const ushort4*)&residb[(size_t)row * 128 + c0i];
        v[0] += b2f(r.x); v[1] += b2f(r.y); v[2] += b2f(r.z); v[3] += b2f(r.w);
      }
      if (LAST) {
        *(f32x4*)&Cf[(size_t)row * 128 + c0i] = v;
      } else {
        *(ushort4*)&Cb[(size_t)row * 128 + c0i] =
            make_ushort4(f2b(v[0]), f2b(v[1]), f2b(v[2]), f2b(v[3]));
      }
    }
  }
}

// ---------------- per-edge: eaee + logits, written at CSR position ----------------
__global__ __launch_bounds__(256) void k_edge(
    const int* __restrict__ esrc, const int* __restrict__ edst,
    const int* __restrict__ epos,
    const float* __restrict__ ea_all, const float* __restrict__ eae,
    const float* __restrict__ attw, const float* __restrict__ ete,
    const float* __restrict__ sd, const float* __restrict__ ss,
    ushort* __restrict__ eaeeB, float* __restrict__ a4buf)
{
  __shared__ float tc[4][4];
  if (threadIdx.x < 16) {
    int tt = threadIdx.x >> 2, h = threadIdx.x & 3;
    float s = 0.f;
    for (int j = 0; j < 16; ++j) s += lrelu(ete[tt * 16 + j]) * attw[(256 + j) * 4 + h];
    tc[tt][h] = s;
  }
  __syncthreads();

  int e = blockIdx.x * 256 + threadIdx.x;
  if (e >= ETOT) return;
  int t = (e < EPROD) ? 0 : (e < EPROD + ESERV) ? 1 : (e < EPROD + ESERV + ETRAN) ? 2 : 3;
  float a0 = ea_all[2 * e], a1 = ea_all[2 * e + 1];
  int s = esrc[e], d = edst[e];
  int pos = epos[e];
  float4 sdv = *(const float4*)&sd[d * 4];
  float4 ssv = *(const float4*)&ss[s * 4];
  float acc[4] = {sdv.x + ssv.x + tc[t][0], sdv.y + ssv.y + tc[t][1],
                  sdv.z + ssv.z + tc[t][2], sdv.w + ssv.w + tc[t][3]};
  ushort us[16];
#pragma unroll
  for (int j = 0; j < 16; ++j) {
    float v = lrelu(a0 * eae[j] + a1 * eae[16 + j]);
    us[j] = f2b(v);
    float4 aw = *(const float4*)&attw[(272 + j) * 4];
    acc[0] += v * aw.x; acc[1] += v * aw.y; acc[2] += v * aw.z; acc[3] += v * aw.w;
  }
  *(ushort4*)&eaeeB[(size_t)pos * 16 + 0]  = make_ushort4(us[0], us[1], us[2], us[3]);
  *(ushort4*)&eaeeB[(size_t)pos * 16 + 4]  = make_ushort4(us[4], us[5], us[6], us[7]);
  *(ushort4*)&eaeeB[(size_t)pos * 16 + 8]  = make_ushort4(us[8], us[9], us[10], us[11]);
  *(ushort4*)&eaeeB[(size_t)pos * 16 + 12] = make_ushort4(us[12], us[13], us[14], us[15]);
  float4 out = {lrelu(acc[0]), lrelu(acc[1]), lrelu(acc[2]), lrelu(acc[3])};
  *(float4*)&a4buf[(size_t)pos * 4] = out;
}

// ---------------- per-node softmax: contiguous CSR reads ----------------
__global__ __launch_bounds__(256) void k_softmax(
    const int* __restrict__ rp,
    const float* __restrict__ a4buf, float* __restrict__ ab)
{
  int n = blockIdx.x * 256 + threadIdx.x;
  if (n >= NTOT) return;
  int beg = rp[n], end = rp[n + 1];
  if (beg == end) return;
  float m0 = -INFINITY, m1 = -INFINITY, m2 = -INFINITY, m3 = -INFINITY;
  for (int i = beg; i < end; ++i) {
    float4 av = *(const float4*)&a4buf[(size_t)i * 4];
    m0 = fmaxf(m0, av.x); m1 = fmaxf(m1, av.y); m2 = fmaxf(m2, av.z); m3 = fmaxf(m3, av.w);
  }
  float d0 = 0.f, d1 = 0.f, d2 = 0.f, d3 = 0.f;
  for (int i = beg; i < end; ++i) {
    float4 av = *(const float4*)&a4buf[(size_t)i * 4];
    d0 += __expf(av.x - m0); d1 += __expf(av.y - m1);
    d2 += __expf(av.z - m2); d3 += __expf(av.w - m3);
  }
  d0 = 1.f / (d0 + 1e-16f); d1 = 1.f / (d1 + 1e-16f);
  d2 = 1.f / (d2 + 1e-16f); d3 = 1.f / (d3 + 1e-16f);
  for (int i = beg; i < end; ++i) {
    float4 av = *(const float4*)&a4buf[(size_t)i * 4];
    ab[i] = 0.25f * (__expf(av.x - m0) * d0 + __expf(av.y - m1) * d1 +
                     __expf(av.z - m2) * d2 + __expf(av.w - m3) * d3);
  }
}

// ---------------- per-dst weighted gather: all CSR-side reads contiguous ----------------
__global__ __launch_bounds__(256) void k_gather(
    const int* __restrict__ rp, const int* __restrict__ srcp,
    const float* __restrict__ ab, const ushort* __restrict__ eaeeB,
    const ushort* __restrict__ xh, ushort* __restrict__ agg)
{
  int wid = (blockIdx.x * 256 + threadIdx.x) >> 6;
  int lane = threadIdx.x & 63;
  if (wid >= NTOT) return;
  int beg = rp[wid], end = rp[wid + 1];
  int deg = end - beg;
  const int l2 = lane & 31;
  const int half = lane >> 5;
  size_t rb = (size_t)wid * AGGW;

  if (deg == 0) {
    *(ushort2*)&agg[rb + lane * 2] = make_ushort2(0, 0);
    if (lane < 16) *(ushort2*)&agg[rb + 128 + lane * 2] = make_ushort2(0, 0);
    return;
  }

  f32x4 axv = (f32x4){0.f, 0.f, 0.f, 0.f};
  float ae0 = 0.f, ae1 = 0.f;

  if (deg <= 64) {
    int sj = 0; float wj = 0.f;
    if (lane < deg) {
      sj = srcp[beg + lane];
      wj = ab[beg + lane];
    }
    for (int j0 = 0; j0 < deg; j0 += 2) {
      int j = j0 + half;
      bool jv = j < deg;
      int jj = jv ? j : 0;
      float wab = jv ? __shfl(wj, jj) : 0.f;
      int s = __shfl(sj, jj);
      ushort4 xv = *(const ushort4*)&xh[(size_t)s * 128 + l2 * 4];
      axv[0] += wab * b2f(xv.x); axv[1] += wab * b2f(xv.y);
      axv[2] += wab * b2f(xv.z); axv[3] += wab * b2f(xv.w);
      if (l2 < 8) {
        ushort2 q = *(const ushort2*)&eaeeB[(size_t)(beg + jj) * 16 + l2 * 2];
        ae0 += wab * b2f(q.x); ae1 += wab * b2f(q.y);
      }
    }
  } else {
    for (int i = beg; i < end; i += 2) {
      int idx = i + half;
      bool valid = idx < end;
      int idc = valid ? idx : beg;
      int s = srcp[idc];
      float w = valid ? ab[idc] : 0.f;
      ushort4 xv = *(const ushort4*)&xh[(size_t)s * 128 + l2 * 4];
      axv[0] += w * b2f(xv.x); axv[1] += w * b2f(xv.y);
      axv[2] += w * b2f(xv.z); axv[3] += w * b2f(xv.w);
      if (l2 < 8) {
        ushort2 q = *(const ushort2*)&eaeeB[(size_t)idc * 16 + l2 * 2];
        ae0 += w * b2f(q.x); ae1 += w * b2f(q.y);
      }
    }
  }
#pragma unroll
  for (int j = 0; j < 4; ++j) axv[j] += __shfl_xor(axv[j], 32);
  ae0 += __shfl_xor(ae0, 32); ae1 += __shfl_xor(ae1, 32);

  if (half == 0) {
    *(ushort4*)&agg[rb + l2 * 4] =
        make_ushort4(f2b(axv[0]), f2b(axv[1]), f2b(axv[2]), f2b(axv[3]));
  } else {
    if (l2 < 8) *(ushort2*)&agg[rb + 128 + l2 * 2] = make_ushort2(f2b(ae0), f2b(ae1));
    else if (l2 < 16) *(ushort2*)&agg[rb + 144 + (l2 - 8) * 2] = make_ushort2(0, 0);
  }
}

// ---------------- launch ----------------
extern "C" void kernel_launch(void* const* d_in, const int* in_sizes, int n_in,
                              void* d_out, int out_size, void* d_ws, size_t ws_size,
                              hipStream_t stream)
{
  const float* x_gen = (const float*)d_in[0];
  const float* x_bus = (const float*)d_in[1];
  const float* x_res = (const float*)d_in[2];
  const int* eip = (const int*)d_in[3];
  const int* eis = (const int*)d_in[4];
  const int* eit = (const int*)d_in[5];
  const int* eib = (const int*)d_in[6];
  const float* eap = (const float*)d_in[7];
  const float* eas = (const float*)d_in[8];
  const float* eat = (const float*)d_in[9];
  const float* eab = (const float*)d_in[10];
  const float* pW_gen = (const float*)d_in[11];
  const float* pb_gen = (const float*)d_in[12];
  const float* pW_bus = (const float*)d_in[13];
  const float* pb_bus = (const float*)d_in[14];
  const float* pW_res = (const float*)d_in[15];
  const float* pb_res = (const float*)d_in[16];

  float* out = (float*)d_out;

  char* p = (char*)d_ws;
  auto alloc = [&](size_t bytes) -> void* {
    void* r = (void*)p;
    p += (bytes + 255) & ~(size_t)255;
    return r;
  };
  int* esrc    = (int*)alloc((size_t)ETOT * 4);
  int* edst    = (int*)alloc((size_t)ETOT * 4);
  float* ea_all = (float*)alloc((size_t)ETOT * 2 * 4);
  int* cnt     = (int*)alloc((size_t)NTOT * 4);
  int* fill    = (int*)alloc((size_t)NTOT * 4);
  int* rp      = (int*)alloc((size_t)(NTOT + 1) * 4);
  int* bsum    = (int*)alloc(1024 * 4);
  int* srcp    = (int*)alloc((size_t)ETOT * 4);
  int* epos    = (int*)alloc((size_t)ETOT * 4);
  float* ab    = (float*)alloc((size_t)ETOT * 4);
  ushort* Wt   = (ushort*)alloc((size_t)233472 * 2);
  ushort* x_bf = (ushort*)alloc((size_t)NTOT * HID * 2);   // activation chain (bf16)
  ushort* xh_bf = (ushort*)alloc((size_t)NTOT * HID * 2);
  float* sd    = (float*)alloc((size_t)NTOT * 4 * 4);
  float* ss    = (float*)alloc((size_t)NTOT * 4 * 4);
  ushort* eaeeB = (ushort*)alloc((size_t)ETOT * 16 * 2);
  float* a4buf = (float*)alloc((size_t)ETOT * 4 * 4);
  ushort* agg  = (ushort*)alloc((size_t)NTOT * AGGW * 2);

  // ---- CSR build ----
  hipMemsetAsync(cnt, 0, (size_t)NTOT * 4, stream);
  hipMemsetAsync(fill, 0, (size_t)NTOT * 4, stream);
  k_setup_edges<<<EB, 256, 0, stream>>>(eip, eis, eit, eib, eap, eas, eat, eab, esrc, edst, ea_all, cnt);
  k_scan1<<<NB_SCAN, 256, 0, stream>>>(cnt, rp, bsum);
  k_scan2<<<1, 1024, 0, stream>>>(bsum, NB_SCAN);
  k_scan3<<<NB_SCAN, 256, 0, stream>>>(rp, bsum);
  k_scatter<<<EB, 256, 0, stream>>>(esrc, edst, rp, fill, srcp, epos);

  // ---- weight conversion ----
  k_convW<<<912, 256, 0, stream>>>(pW_gen, pW_bus, pW_res,
      (const float*)d_in[17], (const float*)d_in[22],
      (const float*)d_in[23], (const float*)d_in[28],
      (const float*)d_in[29], (const float*)d_in[34], Wt);

  const int NB0 = (NGEN + 127) / 128, NB1 = (NBUS + 127) / 128, NB2 = (NRES + 127) / 128;
  const int NBT = NB0 + NB1 + NB2;

  // ---- input projections -> x_bf ----
  {
    Seg s0{x_gen, Wt + 0,     pb_gen, 39, 39, NGEN, NB0, 0};
    Seg s1{x_bus, Wt + 8192,  pb_bus, 16, 16, NBUS, NB1, NGEN};
    Seg s2{x_res, Wt + 16384, pb_res, 16, 16, NRES, NB2, NGEN + NBUS};
    k_mgemm3<<<NBT, 256, 0, stream>>>(s0, s1, s2, 64, x_bf);
  }

  for (int l = 0; l < 3; ++l) {
    const float* hb   = (const float*)d_in[18 + l * 6];
    const float* ete  = (const float*)d_in[19 + l * 6];
    const float* eae  = (const float*)d_in[20 + l * 6];
    const float* attw = (const float*)d_in[21 + l * 6];
    const ushort* WtH = Wt + 24576 + l * 69632;
    const ushort* WtL = Wt + 24576 + l * 69632 + 49152;

    // HeteroLinear + fused attention projections (persistent LDS-W, pipelined, coalesced store)
    k_wgemm_het<<<PGRID, 256, 0, stream>>>(x_bf, WtH, hb, attw, xh_bf, sd, ss);

    k_edge<<<EB, 256, 0, stream>>>(esrc, edst, epos, ea_all, eae, attw, ete, sd, ss, eaeeB, a4buf);
    k_softmax<<<NB_SCAN, 256, 0, stream>>>(rp, a4buf, ab);
    k_gather<<<WB, 256, 0, stream>>>(rp, srcp, ab, eaeeB, xh_bf, agg);

    // x_{l+1} = relu(agg @ linw) + x_l  (bf16 chain; final layer -> fp32 out)
    if (l == 0)      k_wgemm_lin<0,0><<<PGRID, 256, 0, stream>>>(agg, WtL, nullptr, nullptr, x_bf);
    else if (l == 1) k_wgemm_lin<1,0><<<PGRID, 256, 0, stream>>>(agg, WtL, x_bf, nullptr, x_bf);
    else             k_wgemm_lin<1,1><<<PGRID, 256, 0, stream>>>(agg, WtL, x_bf, out, nullptr);
  }
}

// Round 19
// 511.741 us; speedup vs baseline: 1.1017x; 1.0472x over previous
//
#include <hip/hip_runtime.h>
#include <hip/hip_bf16.h>

#define NGEN 50000
#define NBUS 80000
#define NRES 10000
#define NTOT 140000
#define EPROD 100000
#define ESERV 100000
#define ETRAN 150000
#define EBACK 50000
#define ETOT  400000
#define HID 128
#define NEGS 0.2f

#define NB_SCAN 547   // ceil(NTOT/256)
#define EB 1563       // ceil(ETOT/256)
#define WB 35000      // NTOT waves of 64 in 256-thread blocks
#define NW16 8750     // NTOT/16 row-groups
#define PGRID 768     // persistent blocks (3/CU) — 1024 regressed twice (R9, R15)
#define AGGW 160      // agg row width (144 real + 16 pad)
#define LINP 172      // padded LDS row for K=160
#define HETP 140      // padded LDS row for K=128

typedef __attribute__((ext_vector_type(8))) short bf16x8;
typedef __attribute__((ext_vector_type(8))) unsigned short u16x8;
typedef __attribute__((ext_vector_type(4))) float f32x4;

__device__ __forceinline__ float lrelu(float x) { return x >= 0.f ? x : NEGS * x; }
__device__ __forceinline__ float b2f(ushort u) { union { float f; uint i; } v; v.i = (uint)u << 16; return v.f; }
__device__ __forceinline__ ushort f2b(float f) {
  union { float f; uint i; } v; v.f = f;
  return (ushort)((v.i + 0x7FFF + ((v.i >> 16) & 1)) >> 16);
}
__device__ __forceinline__ float i2f(int i) { union { float f; int i; } v; v.i = i; return v.f; }
__device__ __forceinline__ int f2i(float f) { union { float f; int i; } v; v.f = f; return v.i; }

// ---------------- edge setup (+ degree count) ----------------
__global__ __launch_bounds__(256) void k_setup_edges(
    const int* __restrict__ eip, const int* __restrict__ eis,
    const int* __restrict__ eit, const int* __restrict__ eib,
    const float* __restrict__ eap, const float* __restrict__ eas,
    const float* __restrict__ eat, const float* __restrict__ eab,
    int* __restrict__ esrc, int* __restrict__ edst, float* __restrict__ ea_all,
    int* __restrict__ cnt)
{
  int e = blockIdx.x * 256 + threadIdx.x;
  if (e >= ETOT) return;
  int s, d; float a0, a1;
  if (e < EPROD) { s = eip[e]; d = eip[EPROD + e]; a0 = eap[2*e]; a1 = eap[2*e+1]; }
  else if (e < EPROD+ESERV) { int i = e - EPROD; s = eis[i]; d = eis[ESERV + i]; a0 = eas[2*i]; a1 = eas[2*i+1]; }
  else if (e < EPROD+ESERV+ETRAN) { int i = e - EPROD - ESERV; s = eit[i]; d = eit[ETRAN + i]; a0 = eat[2*i]; a1 = eat[2*i+1]; }
  else { int i = e - EPROD - ESERV - ETRAN; s = eib[i]; d = eib[EBACK + i]; a0 = eab[2*i]; a1 = eab[2*i+1]; }
  esrc[e] = s; edst[e] = d; ea_all[2*e] = a0; ea_all[2*e+1] = a1;
  atomicAdd(&cnt[d], 1);
}

// hierarchical scan
__global__ __launch_bounds__(256) void k_scan1(const int* __restrict__ cnt,
                                               int* __restrict__ rp, int* __restrict__ bsum)
{
  int t = threadIdx.x, i = blockIdx.x * 256 + t;
  int v = (i < NTOT) ? cnt[i] : 0;
  __shared__ int buf[256];
  buf[t] = v; __syncthreads();
  for (int off = 1; off < 256; off <<= 1) {
    int x = (t >= off) ? buf[t - off] : 0;
    __syncthreads(); buf[t] += x; __syncthreads();
  }
  if (i < NTOT) rp[i] = buf[t] - v;
  if (t == 255) bsum[blockIdx.x] = buf[255];
}

__global__ __launch_bounds__(1024) void k_scan2(int* __restrict__ bsum, int nb)
{
  int t = threadIdx.x;
  __shared__ int buf[1024];
  int v = (t < nb) ? bsum[t] : 0;
  buf[t] = v; __syncthreads();
  for (int off = 1; off < 1024; off <<= 1) {
    int x = (t >= off) ? buf[t - off] : 0;
    __syncthreads(); buf[t] += x; __syncthreads();
  }
  if (t < nb) bsum[t] = buf[t] - v;
}

__global__ __launch_bounds__(256) void k_scan3(int* __restrict__ rp, const int* __restrict__ bsum)
{
  int i = blockIdx.x * 256 + threadIdx.x;
  if (i < NTOT) rp[i] += bsum[blockIdx.x];
  if (i == 0) rp[NTOT] = ETOT;
}

// scatter: epk[pos] = {src | type<<28, dst, ea0, ea1}; srcp[pos] = src
__global__ __launch_bounds__(256) void k_scatter(const int* __restrict__ esrc,
    const int* __restrict__ edst, const float* __restrict__ ea_all,
    const int* __restrict__ rp, int* __restrict__ fill,
    int4* __restrict__ epk, int* __restrict__ srcp)
{
  int e = blockIdx.x * 256 + threadIdx.x;
  if (e >= ETOT) return;
  int t = (e < EPROD) ? 0 : (e < EPROD + ESERV) ? 1 : (e < EPROD + ESERV + ETRAN) ? 2 : 3;
  int s = esrc[e];
  int d = edst[e];
  int pos = rp[d] + atomicAdd(&fill[d], 1);
  epk[pos] = make_int4(s | (t << 28), d, f2i(ea_all[2*e]), f2i(ea_all[2*e+1]));
  srcp[pos] = s;
}

// ---------------- weight conversion ----------------
__global__ __launch_bounds__(256) void k_convW(
    const float* __restrict__ pg, const float* __restrict__ pb, const float* __restrict__ pr,
    const float* __restrict__ h1, const float* __restrict__ l1,
    const float* __restrict__ h2, const float* __restrict__ l2,
    const float* __restrict__ h3, const float* __restrict__ l3,
    ushort* __restrict__ dst)
{
  int idx = blockIdx.x * 256 + threadIdx.x;
  if (idx >= 233472) return;
  const float* src; int K, KP, base;
  if (idx < 24576) {
    int s = idx >> 13;
    src = (s == 0) ? pg : (s == 1) ? pb : pr;
    K = (s == 0) ? 39 : 16; KP = 64; base = s * 8192;
  } else {
    int r = idx - 24576, l = r / 69632, q = r % 69632;
    const float* h = (l == 0) ? h1 : (l == 1) ? h2 : h3;
    const float* lw = (l == 0) ? l1 : (l == 1) ? l2 : l3;
    if (q < 49152) { int t = q >> 14; src = h + t * 16384; K = 128; KP = 128; base = 24576 + l * 69632 + t * 16384; }
    else { src = lw; K = 144; KP = 160; base = 24576 + l * 69632 + 49152; }
  }
  int li = idx - base, c = li / KP, k = li % KP;
  dst[idx] = (k < K) ? f2b(src[k * 128 + c]) : (ushort)0;
}

// ---------------- segmented LDS GEMM (input projections only, K<=39) ----------------
struct Seg {
  const void* A; const ushort* Wt; const float* bias;
  int lda, K, M, nb, rbase;
};

__global__ __launch_bounds__(256) void k_mgemm3(Seg s0, Seg s1, Seg s2, int KP, ushort* __restrict__ Cb)
{
  __shared__ ushort As[128][72];
  __shared__ ushort Bs[128][72];
  int bid = blockIdx.x;
  Seg sg = s0;
  if (bid >= s0.nb + s1.nb) { sg = s2; bid -= s0.nb + s1.nb; }
  else if (bid >= s0.nb) { sg = s1; bid -= s0.nb; }

  const int tid = threadIdx.x;
  const int lr = tid & 15, hi = (tid & 63) >> 4;
  const int w = tid >> 6;
  const int wrow = (w >> 1) * 64, wcol = (w & 1) * 64;
  const int brow = bid * 128;

  f32x4 acc[4][4];
#pragma unroll
  for (int m = 0; m < 4; ++m)
#pragma unroll
    for (int n = 0; n < 4; ++n) acc[m][n] = (f32x4){0.f, 0.f, 0.f, 0.f};

  for (int k0 = 0; k0 < KP; k0 += 64) {
#pragma unroll
    for (int p = 0; p < 8; ++p) {
      int li = tid + 256 * p;
      int row = li >> 4, c4 = (li & 15) * 4;
      int gr = brow + row, gk = k0 + c4;
      ushort4 u = make_ushort4(0, 0, 0, 0);
      if (gr < sg.M) {
        const float* A = (const float*)sg.A;
        const float* ar = A + (size_t)gr * sg.lda;
        if (gk + 0 < sg.K) u.x = f2b(ar[gk + 0]);
        if (gk + 1 < sg.K) u.y = f2b(ar[gk + 1]);
        if (gk + 2 < sg.K) u.z = f2b(ar[gk + 2]);
        if (gk + 3 < sg.K) u.w = f2b(ar[gk + 3]);
      }
      *(ushort4*)&As[row][c4] = u;
    }
#pragma unroll
    for (int p = 0; p < 8; ++p) {
      int li = tid + 256 * p;
      int row = li >> 4, c4 = (li & 15) * 4;
      *(ushort4*)&Bs[row][c4] = *(const ushort4*)&sg.Wt[(size_t)row * KP + k0 + c4];
    }
    __syncthreads();
#pragma unroll
    for (int kk = 0; kk < 64; kk += 32) {
      bf16x8 af[4], bfv[4];
#pragma unroll
      for (int m = 0; m < 4; ++m) af[m] = *(const bf16x8*)&As[wrow + m * 16 + lr][kk + hi * 8];
#pragma unroll
      for (int n = 0; n < 4; ++n) bfv[n] = *(const bf16x8*)&Bs[wcol + n * 16 + lr][kk + hi * 8];
#pragma unroll
      for (int m = 0; m < 4; ++m)
#pragma unroll
        for (int n = 0; n < 4; ++n)
          acc[m][n] = __builtin_amdgcn_mfma_f32_16x16x32_bf16(af[m], bfv[n], acc[m][n], 0, 0, 0);
    }
    __syncthreads();
  }

#pragma unroll
  for (int m = 0; m < 4; ++m) {
#pragma unroll
    for (int j = 0; j < 4; ++j) {
      int gr = brow + wrow + m * 16 + hi * 4 + j;
      if (gr >= sg.M) continue;
#pragma unroll
      for (int n = 0; n < 4; ++n) {
        int col = wcol + n * 16 + lr;
        float v = acc[m][n][j] + sg.bias[col];
        Cb[(size_t)(sg.rbase + gr) * 128 + col] = f2b(v);
      }
    }
  }
}

// ---------------- persistent LDS-W wave GEMM (A-pipelined, coalesced xh store): hetero + attproj ----------------
__global__ __launch_bounds__(256) void k_wgemm_het(
    const ushort* __restrict__ A,      // [NTOT][128] bf16
    const ushort* __restrict__ WtH,    // 3 x [128 col][128 k] bf16
    const float* __restrict__ hb,      // [3][128]
    const float* __restrict__ attw,    // [288][4]
    ushort* __restrict__ xh,           // [NTOT][128] bf16
    float* __restrict__ sd, float* __restrict__ ss)
{
  __shared__ ushort Ws[128 * HETP];
  __shared__ ushort Xb[4][16][136];    // wave-private xh staging (padded; 17 KB)
  const int tid = threadIdx.x;
  const int bid = blockIdx.x;
  int seg, lb, nb, ntile, segbase, segrows;
  if (bid < 274)      { seg = 0; lb = bid;       nb = 274; ntile = 782;  segbase = 0;           segrows = NGEN; }
  else if (bid < 712) { seg = 1; lb = bid - 274; nb = 438; ntile = 1250; segbase = NGEN;        segrows = NBUS; }
  else                { seg = 2; lb = bid - 712; nb = 56;  ntile = 157;  segbase = NGEN + NBUS; segrows = NRES; }

  const int w = tid >> 6;
  const int lane = tid & 63;
  const int lr = lane & 15, hi = lane >> 4;

  // prologue: issue tile lb's A-loads BEFORE staging (latency hides under staging+barrier)
  int rl = lb * 64 + w * 16;
  int valid = rl < segrows;
  int r0 = segbase + (valid ? rl : 0);
  const ushort* Ap = A + (size_t)(r0 + lr) * 128 + hi * 8;
  bf16x8 a0 = *(const bf16x8*)(Ap);
  bf16x8 a1 = *(const bf16x8*)(Ap + 32);
  bf16x8 a2 = *(const bf16x8*)(Ap + 64);
  bf16x8 a3 = *(const bf16x8*)(Ap + 96);

  // stage seg W: [128][128] -> padded [128][HETP]
  {
    const ushort* src = WtH + seg * 16384 + tid * 64;
    ushort* dstl = Ws + (tid >> 1) * HETP + (tid & 1) * 64;
#pragma unroll
    for (int j = 0; j < 8; ++j)
      *(u16x8*)&dstl[j * 8] = *(const u16x8*)&src[j * 8];
  }
  __syncthreads();

  const float* bias = hb + seg * 128;

  for (int t = lb; t < ntile; t += nb) {
    const int curvalid = valid, currow = r0;
    bf16x8 c0 = a0, c1 = a1, c2 = a2, c3 = a3;

    int tn = t + nb;
    if (tn < ntile) {
      rl = tn * 64 + w * 16;
      valid = rl < segrows;
      r0 = segbase + (valid ? rl : 0);
      const ushort* An = A + (size_t)(r0 + lr) * 128 + hi * 8;
      a0 = *(const bf16x8*)(An);
      a1 = *(const bf16x8*)(An + 32);
      a2 = *(const bf16x8*)(An + 64);
      a3 = *(const bf16x8*)(An + 96);
    }
    if (!curvalid) continue;

    f32x4 acc[8];
#pragma unroll
    for (int n = 0; n < 8; ++n) acc[n] = (f32x4){0.f, 0.f, 0.f, 0.f};
    const ushort* wb0 = Ws + lr * HETP + hi * 8;
#pragma unroll
    for (int n = 0; n < 8; ++n) {
      const ushort* wn = wb0 + n * 16 * HETP;
      acc[n] = __builtin_amdgcn_mfma_f32_16x16x32_bf16(*(const bf16x8*)(wn),      c0, acc[n], 0, 0, 0);
      acc[n] = __builtin_amdgcn_mfma_f32_16x16x32_bf16(*(const bf16x8*)(wn + 32), c1, acc[n], 0, 0, 0);
      acc[n] = __builtin_amdgcn_mfma_f32_16x16x32_bf16(*(const bf16x8*)(wn + 64), c2, acc[n], 0, 0, 0);
      acc[n] = __builtin_amdgcn_mfma_f32_16x16x32_bf16(*(const bf16x8*)(wn + 96), c3, acc[n], 0, 0, 0);
    }

    float pd0 = 0.f, pd1 = 0.f, pd2 = 0.f, pd3 = 0.f;
    float ps0 = 0.f, ps1 = 0.f, ps2 = 0.f, ps3 = 0.f;
#pragma unroll
    for (int n = 0; n < 8; ++n) {
      int c0i = n * 16 + hi * 4;
      float4 bv = *(const float4*)&bias[c0i];
      f32x4 v = acc[n];
      v[0] += bv.x; v[1] += bv.y; v[2] += bv.z; v[3] += bv.w;
      *(ushort4*)&Xb[w][lr][c0i] = make_ushort4(f2b(v[0]), f2b(v[1]), f2b(v[2]), f2b(v[3]));
#pragma unroll
      for (int j = 0; j < 4; ++j) {
        float4 wd = *(const float4*)&attw[(c0i + j) * 4];
        float4 ws = *(const float4*)&attw[(128 + c0i + j) * 4];
        pd0 += v[j] * wd.x; pd1 += v[j] * wd.y; pd2 += v[j] * wd.z; pd3 += v[j] * wd.w;
        ps0 += v[j] * ws.x; ps1 += v[j] * ws.y; ps2 += v[j] * ws.z; ps3 += v[j] * ws.w;
      }
    }
    // coalesced xh store: 4 x 1KB contiguous (rows currow..currow+15)
#pragma unroll
    for (int k4 = 0; k4 < 4; ++k4) {
      int rrow = k4 * 4 + hi;
      int ccol = lr * 8;
      u16x8 val = *(const u16x8*)&Xb[w][rrow][ccol];
      *(u16x8*)&xh[(size_t)(currow + rrow) * 128 + ccol] = val;
    }
    const int row = currow + lr;
    pd0 += __shfl_xor(pd0, 16); pd0 += __shfl_xor(pd0, 32);
    pd1 += __shfl_xor(pd1, 16); pd1 += __shfl_xor(pd1, 32);
    pd2 += __shfl_xor(pd2, 16); pd2 += __shfl_xor(pd2, 32);
    pd3 += __shfl_xor(pd3, 16); pd3 += __shfl_xor(pd3, 32);
    ps0 += __shfl_xor(ps0, 16); ps0 += __shfl_xor(ps0, 32);
    ps1 += __shfl_xor(ps1, 16); ps1 += __shfl_xor(ps1, 32);
    ps2 += __shfl_xor(ps2, 16); ps2 += __shfl_xor(ps2, 32);
    ps3 += __shfl_xor(ps3, 16); ps3 += __shfl_xor(ps3, 32);
    if (hi == 0) {
      float4 o = {pd0, pd1, pd2, pd3};
      *(float4*)&sd[row * 4] = o;
    } else if (hi == 1) {
      float4 o = {ps0, ps1, ps2, ps3};
      *(float4*)&ss[row * 4] = o;
    }
  }
}

// ---------------- persistent LDS-W wave GEMM (pipelined): linw (K=160), relu + bf16 resid chain ----------------
template<int HASRES, int LAST>
__global__ __launch_bounds__(256) void k_wgemm_lin(
    const ushort* __restrict__ A,      // agg [NTOT][160] bf16 (cols 144.. zero)
    const ushort* __restrict__ Wt,     // [128 col][160 k] bf16 (k 144.. zero)
    const ushort* residb,              // bf16 resid (may alias Cb; row-exclusive)
    float* __restrict__ Cf,            // [NTOT][128] fp32 (LAST)
    ushort* Cb)                        // [NTOT][128] bf16 (!LAST)
{
  __shared__ ushort Ws[128 * LINP];
  const int tid = threadIdx.x;
  const int lane = tid & 63;
  const int lr = lane & 15, hi = lane >> 4;
  const int w = tid >> 6;

  int gw = blockIdx.x * 4 + w;      // < 3072 < NW16 always
  const ushort* Ar0 = A + (size_t)(gw * 16 + lr) * AGGW + hi * 8;
  bf16x8 a0 = *(const bf16x8*)(Ar0);
  bf16x8 a1 = *(const bf16x8*)(Ar0 + 32);
  bf16x8 a2 = *(const bf16x8*)(Ar0 + 64);
  bf16x8 a3 = *(const bf16x8*)(Ar0 + 96);
  bf16x8 a4 = *(const bf16x8*)(Ar0 + 128);

  {
    const ushort* src = Wt + tid * 80;
    ushort* dstl = Ws + (tid >> 1) * LINP + (tid & 1) * 80;
#pragma unroll
    for (int j = 0; j < 10; ++j)
      *(u16x8*)&dstl[j * 8] = *(const u16x8*)&src[j * 8];
  }
  __syncthreads();

  for (; gw < NW16; gw += PGRID * 4) {
    const int gcur = gw;
    bf16x8 c0 = a0, c1 = a1, c2 = a2, c3 = a3, c4 = a4;
    int gn = gw + PGRID * 4;
    if (gn < NW16) {
      const ushort* An = A + (size_t)(gn * 16 + lr) * AGGW + hi * 8;
      a0 = *(const bf16x8*)(An);
      a1 = *(const bf16x8*)(An + 32);
      a2 = *(const bf16x8*)(An + 64);
      a3 = *(const bf16x8*)(An + 96);
      a4 = *(const bf16x8*)(An + 128);
    }

    f32x4 acc[8];
#pragma unroll
    for (int n = 0; n < 8; ++n) acc[n] = (f32x4){0.f, 0.f, 0.f, 0.f};
    const ushort* wb0 = Ws + lr * LINP + hi * 8;
#pragma unroll
    for (int n = 0; n < 8; ++n) {
      const ushort* wn = wb0 + n * 16 * LINP;
      acc[n] = __builtin_amdgcn_mfma_f32_16x16x32_bf16(*(const bf16x8*)(wn),       c0, acc[n], 0, 0, 0);
      acc[n] = __builtin_amdgcn_mfma_f32_16x16x32_bf16(*(const bf16x8*)(wn + 32),  c1, acc[n], 0, 0, 0);
      acc[n] = __builtin_amdgcn_mfma_f32_16x16x32_bf16(*(const bf16x8*)(wn + 64),  c2, acc[n], 0, 0, 0);
      acc[n] = __builtin_amdgcn_mfma_f32_16x16x32_bf16(*(const bf16x8*)(wn + 96),  c3, acc[n], 0, 0, 0);
      acc[n] = __builtin_amdgcn_mfma_f32_16x16x32_bf16(*(const bf16x8*)(wn + 128), c4, acc[n], 0, 0, 0);
    }

    const int row = gcur * 16 + lr;
#pragma unroll
    for (int n = 0; n < 8; ++n) {
      int c0i = n * 16 + hi * 4;
      f32x4 v = acc[n];
      v[0] = fmaxf(v[0], 0.f); v[1] = fmaxf(v[1], 0.f);
      v[2] = fmaxf(v[2], 0.f); v[3] = fmaxf(v[3], 0.f);
      if (HASRES) {
        ushort4 r = *(const ushort4*)&residb[(size_t)row * 128 + c0i];
        v[0] += b2f(r.x); v[1] += b2f(r.y); v[2] += b2f(r.z); v[3] += b2f(r.w);
      }
      if (LAST) {
        *(f32x4*)&Cf[(size_t)row * 128 + c0i] = v;
      } else {
        *(ushort4*)&Cb[(size_t)row * 128 + c0i] =
            make_ushort4(f2b(v[0]), f2b(v[1]), f2b(v[2]), f2b(v[3]));
      }
    }
  }
}

// ---------------- per-edge (CSR-position order, fully streaming): eaee + logits ----------------
__global__ __launch_bounds__(256) void k_edge(
    const int4* __restrict__ epk,
    const float* __restrict__ eae,
    const float* __restrict__ attw, const float* __restrict__ ete,
    const float* __restrict__ sd, const float* __restrict__ ss,
    ushort* __restrict__ eaeeB, float* __restrict__ a4buf)
{
  __shared__ float tc[4][4];
  if (threadIdx.x < 16) {
    int tt = threadIdx.x >> 2, h = threadIdx.x & 3;
    float s = 0.f;
    for (int j = 0; j < 16; ++j) s += lrelu(ete[tt * 16 + j]) * attw[(256 + j) * 4 + h];
    tc[tt][h] = s;
  }
  __syncthreads();

  int pos = blockIdx.x * 256 + threadIdx.x;
  if (pos >= ETOT) return;
  int4 pk = epk[pos];
  int s = pk.x & 0x0FFFFFFF;
  int t = (pk.x >> 28) & 3;
  int d = pk.y;
  float a0 = i2f(pk.z), a1 = i2f(pk.w);
  float4 sdv = *(const float4*)&sd[d * 4];
  float4 ssv = *(const float4*)&ss[s * 4];
  float acc[4] = {sdv.x + ssv.x + tc[t][0], sdv.y + ssv.y + tc[t][1],
                  sdv.z + ssv.z + tc[t][2], sdv.w + ssv.w + tc[t][3]};
  ushort us[16];
#pragma unroll
  for (int j = 0; j < 16; ++j) {
    float v = lrelu(a0 * eae[j] + a1 * eae[16 + j]);
    us[j] = f2b(v);
    float4 aw = *(const float4*)&attw[(272 + j) * 4];
    acc[0] += v * aw.x; acc[1] += v * aw.y; acc[2] += v * aw.z; acc[3] += v * aw.w;
  }
  *(ushort4*)&eaeeB[(size_t)pos * 16 + 0]  = make_ushort4(us[0], us[1], us[2], us[3]);
  *(ushort4*)&eaeeB[(size_t)pos * 16 + 4]  = make_ushort4(us[4], us[5], us[6], us[7]);
  *(ushort4*)&eaeeB[(size_t)pos * 16 + 8]  = make_ushort4(us[8], us[9], us[10], us[11]);
  *(ushort4*)&eaeeB[(size_t)pos * 16 + 12] = make_ushort4(us[12], us[13], us[14], us[15]);
  float4 out = {lrelu(acc[0]), lrelu(acc[1]), lrelu(acc[2]), lrelu(acc[3])};
  *(float4*)&a4buf[(size_t)pos * 4] = out;
}

// ---------------- per-node softmax: contiguous CSR reads ----------------
__global__ __launch_bounds__(256) void k_softmax(
    const int* __restrict__ rp,
    const float* __restrict__ a4buf, float* __restrict__ ab)
{
  int n = blockIdx.x * 256 + threadIdx.x;
  if (n >= NTOT) return;
  int beg = rp[n], end = rp[n + 1];
  if (beg == end) return;
  float m0 = -INFINITY, m1 = -INFINITY, m2 = -INFINITY, m3 = -INFINITY;
  for (int i = beg; i < end; ++i) {
    float4 av = *(const float4*)&a4buf[(size_t)i * 4];
    m0 = fmaxf(m0, av.x); m1 = fmaxf(m1, av.y); m2 = fmaxf(m2, av.z); m3 = fmaxf(m3, av.w);
  }
  float d0 = 0.f, d1 = 0.f, d2 = 0.f, d3 = 0.f;
  for (int i = beg; i < end; ++i) {
    float4 av = *(const float4*)&a4buf[(size_t)i * 4];
    d0 += __expf(av.x - m0); d1 += __expf(av.y - m1);
    d2 += __expf(av.z - m2); d3 += __expf(av.w - m3);
  }
  d0 = 1.f / (d0 + 1e-16f); d1 = 1.f / (d1 + 1e-16f);
  d2 = 1.f / (d2 + 1e-16f); d3 = 1.f / (d3 + 1e-16f);
  for (int i = beg; i < end; ++i) {
    float4 av = *(const float4*)&a4buf[(size_t)i * 4];
    ab[i] = 0.25f * (__expf(av.x - m0) * d0 + __expf(av.y - m1) * d1 +
                     __expf(av.z - m2) * d2 + __expf(av.w - m3) * d3);
  }
}

// ---------------- per-dst weighted gather: all CSR-side reads contiguous ----------------
__global__ __launch_bounds__(256) void k_gather(
    const int* __restrict__ rp, const int* __restrict__ srcp,
    const float* __restrict__ ab, const ushort* __restrict__ eaeeB,
    const ushort* __restrict__ xh, ushort* __restrict__ agg)
{
  int wid = (blockIdx.x * 256 + threadIdx.x) >> 6;
  int lane = threadIdx.x & 63;
  if (wid >= NTOT) return;
  int beg = rp[wid], end = rp[wid + 1];
  int deg = end - beg;
  const int l2 = lane & 31;
  const int half = lane >> 5;
  size_t rb = (size_t)wid * AGGW;

  if (deg == 0) {
    *(ushort2*)&agg[rb + lane * 2] = make_ushort2(0, 0);
    if (lane < 16) *(ushort2*)&agg[rb + 128 + lane * 2] = make_ushort2(0, 0);
    return;
  }

  f32x4 axv = (f32x4){0.f, 0.f, 0.f, 0.f};
  float ae0 = 0.f, ae1 = 0.f;

  if (deg <= 64) {
    int sj = 0; float wj = 0.f;
    if (lane < deg) {
      sj = srcp[beg + lane];
      wj = ab[beg + lane];
    }
    for (int j0 = 0; j0 < deg; j0 += 2) {
      int j = j0 + half;
      bool jv = j < deg;
      int jj = jv ? j : 0;
      float wab = jv ? __shfl(wj, jj) : 0.f;
      int s = __shfl(sj, jj);
      ushort4 xv = *(const ushort4*)&xh[(size_t)s * 128 + l2 * 4];
      axv[0] += wab * b2f(xv.x); axv[1] += wab * b2f(xv.y);
      axv[2] += wab * b2f(xv.z); axv[3] += wab * b2f(xv.w);
      if (l2 < 8) {
        ushort2 q = *(const ushort2*)&eaeeB[(size_t)(beg + jj) * 16 + l2 * 2];
        ae0 += wab * b2f(q.x); ae1 += wab * b2f(q.y);
      }
    }
  } else {
    for (int i = beg; i < end; i += 2) {
      int idx = i + half;
      bool valid = idx < end;
      int idc = valid ? idx : beg;
      int s = srcp[idc];
      float w = valid ? ab[idc] : 0.f;
      ushort4 xv = *(const ushort4*)&xh[(size_t)s * 128 + l2 * 4];
      axv[0] += w * b2f(xv.x); axv[1] += w * b2f(xv.y);
      axv[2] += w * b2f(xv.z); axv[3] += w * b2f(xv.w);
      if (l2 < 8) {
        ushort2 q = *(const ushort2*)&eaeeB[(size_t)idc * 16 + l2 * 2];
        ae0 += w * b2f(q.x); ae1 += w * b2f(q.y);
      }
    }
  }
#pragma unroll
  for (int j = 0; j < 4; ++j) axv[j] += __shfl_xor(axv[j], 32);
  ae0 += __shfl_xor(ae0, 32); ae1 += __shfl_xor(ae1, 32);

  if (half == 0) {
    *(ushort4*)&agg[rb + l2 * 4] =
        make_ushort4(f2b(axv[0]), f2b(axv[1]), f2b(axv[2]), f2b(axv[3]));
  } else {
    if (l2 < 8) *(ushort2*)&agg[rb + 128 + l2 * 2] = make_ushort2(f2b(ae0), f2b(ae1));
    else if (l2 < 16) *(ushort2*)&agg[rb + 144 + (l2 - 8) * 2] = make_ushort2(0, 0);
  }
}

// ---------------- launch ----------------
extern "C" void kernel_launch(void* const* d_in, const int* in_sizes, int n_in,
                              void* d_out, int out_size, void* d_ws, size_t ws_size,
                              hipStream_t stream)
{
  const float* x_gen = (const float*)d_in[0];
  const float* x_bus = (const float*)d_in[1];
  const float* x_res = (const float*)d_in[2];
  const int* eip = (const int*)d_in[3];
  const int* eis = (const int*)d_in[4];
  const int* eit = (const int*)d_in[5];
  const int* eib = (const int*)d_in[6];
  const float* eap = (const float*)d_in[7];
  const float* eas = (const float*)d_in[8];
  const float* eat = (const float*)d_in[9];
  const float* eab = (const float*)d_in[10];
  const float* pW_gen = (const float*)d_in[11];
  const float* pb_gen = (const float*)d_in[12];
  const float* pW_bus = (const float*)d_in[13];
  const float* pb_bus = (const float*)d_in[14];
  const float* pW_res = (const float*)d_in[15];
  const float* pb_res = (const float*)d_in[16];

  float* out = (float*)d_out;

  char* p = (char*)d_ws;
  auto alloc = [&](size_t bytes) -> void* {
    void* r = (void*)p;
    p += (bytes + 255) & ~(size_t)255;
    return r;
  };
  int* esrc    = (int*)alloc((size_t)ETOT * 4);
  int* edst    = (int*)alloc((size_t)ETOT * 4);
  float* ea_all = (float*)alloc((size_t)ETOT * 2 * 4);
  int* cnt     = (int*)alloc((size_t)NTOT * 4);
  int* fill    = (int*)alloc((size_t)NTOT * 4);
  int* rp      = (int*)alloc((size_t)(NTOT + 1) * 4);
  int* bsum    = (int*)alloc(1024 * 4);
  int4* epk    = (int4*)alloc((size_t)ETOT * 16);
  int* srcp    = (int*)alloc((size_t)ETOT * 4);
  float* ab    = (float*)alloc((size_t)ETOT * 4);
  ushort* Wt   = (ushort*)alloc((size_t)233472 * 2);
  ushort* x_bf = (ushort*)alloc((size_t)NTOT * HID * 2);   // activation chain (bf16)
  ushort* xh_bf = (ushort*)alloc((size_t)NTOT * HID * 2);
  float* sd    = (float*)alloc((size_t)NTOT * 4 * 4);
  float* ss    = (float*)alloc((size_t)NTOT * 4 * 4);
  ushort* eaeeB = (ushort*)alloc((size_t)ETOT * 16 * 2);
  float* a4buf = (float*)alloc((size_t)ETOT * 4 * 4);
  ushort* agg  = (ushort*)alloc((size_t)NTOT * AGGW * 2);

  // ---- CSR build ----
  hipMemsetAsync(cnt, 0, (size_t)NTOT * 4, stream);
  hipMemsetAsync(fill, 0, (size_t)NTOT * 4, stream);
  k_setup_edges<<<EB, 256, 0, stream>>>(eip, eis, eit, eib, eap, eas, eat, eab, esrc, edst, ea_all, cnt);
  k_scan1<<<NB_SCAN, 256, 0, stream>>>(cnt, rp, bsum);
  k_scan2<<<1, 1024, 0, stream>>>(bsum, NB_SCAN);
  k_scan3<<<NB_SCAN, 256, 0, stream>>>(rp, bsum);
  k_scatter<<<EB, 256, 0, stream>>>(esrc, edst, ea_all, rp, fill, epk, srcp);

  // ---- weight conversion ----
  k_convW<<<912, 256, 0, stream>>>(pW_gen, pW_bus, pW_res,
      (const float*)d_in[17], (const float*)d_in[22],
      (const float*)d_in[23], (const float*)d_in[28],
      (const float*)d_in[29], (const float*)d_in[34], Wt);

  const int NB0 = (NGEN + 127) / 128, NB1 = (NBUS + 127) / 128, NB2 = (NRES + 127) / 128;
  const int NBT = NB0 + NB1 + NB2;

  // ---- input projections -> x_bf ----
  {
    Seg s0{x_gen, Wt + 0,     pb_gen, 39, 39, NGEN, NB0, 0};
    Seg s1{x_bus, Wt + 8192,  pb_bus, 16, 16, NBUS, NB1, NGEN};
    Seg s2{x_res, Wt + 16384, pb_res, 16, 16, NRES, NB2, NGEN + NBUS};
    k_mgemm3<<<NBT, 256, 0, stream>>>(s0, s1, s2, 64, x_bf);
  }

  for (int l = 0; l < 3; ++l) {
    const float* hb   = (const float*)d_in[18 + l * 6];
    const float* ete  = (const float*)d_in[19 + l * 6];
    const float* eae  = (const float*)d_in[20 + l * 6];
    const float* attw = (const float*)d_in[21 + l * 6];
    const ushort* WtH = Wt + 24576 + l * 69632;
    const ushort* WtL = Wt + 24576 + l * 69632 + 49152;

    // HeteroLinear + fused attention projections (persistent LDS-W, pipelined, coalesced store)
    k_wgemm_het<<<PGRID, 256, 0, stream>>>(x_bf, WtH, hb, attw, xh_bf, sd, ss);

    k_edge<<<EB, 256, 0, stream>>>(epk, eae, attw, ete, sd, ss, eaeeB, a4buf);
    k_softmax<<<NB_SCAN, 256, 0, stream>>>(rp, a4buf, ab);
    k_gather<<<WB, 256, 0, stream>>>(rp, srcp, ab, eaeeB, xh_bf, agg);

    // x_{l+1} = relu(agg @ linw) + x_l  (bf16 chain; final layer -> fp32 out)
    if (l == 0)      k_wgemm_lin<0,0><<<PGRID, 256, 0, stream>>>(agg, WtL, nullptr, nullptr, x_bf);
    else if (l == 1) k_wgemm_lin<1,0><<<PGRID, 256, 0, stream>>>(agg, WtL, x_bf, nullptr, x_bf);
    else             k_wgemm_lin<1,1><<<PGRID, 256, 0, stream>>>(agg, WtL, x_bf, out, nullptr);
  }
}